// Round 2
// baseline (8446.963 us; speedup 1.0000x reference)
//
#include <hip/hip_runtime.h>
#include <hip/hip_bf16.h>

// Problem constants (DeepSeek-V2-style scaled config)
#define S 2048
#define D 1024
#define H 16
#define DH 64
#define LAYERS 2
#define E 8
#define I_DIM 512
#define SI 1024
#define V 32000

// ---------------------------------------------------------------------------
// Embedding lookup: h[s,d] = embed[tok[s], d], vectorized x4
// ---------------------------------------------------------------------------
__global__ __launch_bounds__(256) void embed_k(const int* __restrict__ tok,
                                               const float* __restrict__ emb,
                                               float* __restrict__ h) {
  int idx = blockIdx.x * 256 + threadIdx.x;      // over S*D/4
  if (idx >= S * D / 4) return;
  int s = idx >> 8;                               // D/4 = 256 vec4 per row
  int d4 = idx & 255;
  int t = tok[s];
  float4 u = *(const float4*)(emb + (size_t)t * D + d4 * 4);
  *(float4*)(h + (size_t)s * D + d4 * 4) = u;
}

// ---------------------------------------------------------------------------
// RMSNorm: x[s,:] = h[s,:] * rsqrt(mean(h^2)+1e-6) * w
// ---------------------------------------------------------------------------
__global__ __launch_bounds__(256) void rmsnorm_k(const float* __restrict__ h,
                                                 const float* __restrict__ w,
                                                 float* __restrict__ x) {
  int s = blockIdx.x, tid = threadIdx.x;
  __shared__ float red[256];
  float4 hv = *(const float4*)(h + (size_t)s * D + tid * 4);
  red[tid] = hv.x * hv.x + hv.y * hv.y + hv.z * hv.z + hv.w * hv.w;
  __syncthreads();
  for (int st = 128; st > 0; st >>= 1) {
    if (tid < st) red[tid] += red[tid + st];
    __syncthreads();
  }
  float inv = rsqrtf(red[0] * (1.0f / 1024.0f) + 1e-6f);
  float4 wv = *(const float4*)(w + tid * 4);
  float4 o;
  o.x = hv.x * inv * wv.x;
  o.y = hv.y * inv * wv.y;
  o.z = hv.z * inv * wv.z;
  o.w = hv.w * inv * wv.w;
  *(float4*)(x + (size_t)s * D + tid * 4) = o;
}

// ---------------------------------------------------------------------------
// Generic tiled GEMM: C[M,N] (f32) = A[M,K](f32) @ B[N,K](f32)^T
// 64x64 tile, 256 threads, 4x4 microtile, K-tile 16.
// ACC: C += result.  EXPERT: B is down_projs [E][D][I], K spans E*I.
// ---------------------------------------------------------------------------
template <int ACC, int EXPERT>
__global__ __launch_bounds__(256) void gemm_bt_k(const float* __restrict__ A, int lda,
                                                 const float* __restrict__ B, int ldb,
                                                 float* __restrict__ C, int ldc, int K) {
  __shared__ float As[16][68];
  __shared__ float Bs[16][68];
  int tid = threadIdx.x;
  int n0 = blockIdx.x * 64;
  int m0 = blockIdx.y * 64;
  int tx = tid & 15, ty = tid >> 4;
  int lr = tid >> 2;            // 0..63 (tile row for loading)
  int lc = (tid & 3) << 2;      // 0,4,8,12 (k offset for loading)
  float acc[4][4] = {};
  const float* Ap = A + (size_t)(m0 + lr) * lda + lc;
  for (int k0 = 0; k0 < K; k0 += 16) {
    float4 a = *(const float4*)(Ap + k0);
    As[lc + 0][lr] = a.x; As[lc + 1][lr] = a.y;
    As[lc + 2][lr] = a.z; As[lc + 3][lr] = a.w;
    const float* bp;
    if (EXPERT) {
      int e = k0 >> 9, koff = k0 & 511;  // K-tile never crosses expert boundary
      bp = B + ((size_t)(e * D + n0 + lr)) * I_DIM + koff + lc;
    } else {
      bp = B + (size_t)(n0 + lr) * ldb + k0 + lc;
    }
    float4 b = *(const float4*)bp;
    Bs[lc + 0][lr] = b.x; Bs[lc + 1][lr] = b.y;
    Bs[lc + 2][lr] = b.z; Bs[lc + 3][lr] = b.w;
    __syncthreads();
#pragma unroll
    for (int kk = 0; kk < 16; kk++) {
      float4 av = *(const float4*)&As[kk][ty << 2];
      float4 bv = *(const float4*)&Bs[kk][tx << 2];
      acc[0][0] += av.x * bv.x; acc[0][1] += av.x * bv.y;
      acc[0][2] += av.x * bv.z; acc[0][3] += av.x * bv.w;
      acc[1][0] += av.y * bv.x; acc[1][1] += av.y * bv.y;
      acc[1][2] += av.y * bv.z; acc[1][3] += av.y * bv.w;
      acc[2][0] += av.z * bv.x; acc[2][1] += av.z * bv.y;
      acc[2][2] += av.z * bv.z; acc[2][3] += av.z * bv.w;
      acc[3][0] += av.w * bv.x; acc[3][1] += av.w * bv.y;
      acc[3][2] += av.w * bv.z; acc[3][3] += av.w * bv.w;
    }
    __syncthreads();
  }
#pragma unroll
  for (int i = 0; i < 4; i++) {
    float4* cp = (float4*)(C + (size_t)(m0 + (ty << 2) + i) * ldc + n0 + (tx << 2));
    float4 val = {acc[i][0], acc[i][1], acc[i][2], acc[i][3]};
    if (ACC) {
      float4 old = *cp;
      val.x += old.x; val.y += old.y; val.z += old.z; val.w += old.w;
    }
    *cp = val;
  }
}

// ---------------------------------------------------------------------------
// RoPE applied in-place to q and k.
// ---------------------------------------------------------------------------
__global__ __launch_bounds__(256) void rope_k(float* __restrict__ q, float* __restrict__ k) {
  int idx = blockIdx.x * 256 + threadIdx.x;   // S*H*32 = 1048576
  int s = idx >> 9;                           // / (H*32)
  int r = idx & 511;
  int hd = r >> 5, i = r & 31;
  // inv_freq = 10000^(-i/32)
  float invf = expf(-(float)i * (9.210340371976184f / 32.0f));
  float ang = (float)s * invf;
  float c = cosf(ang), sn = sinf(ang);
  int base = s * D + hd * DH + i;
  float q1 = q[base], q2 = q[base + 32];
  q[base] = q1 * c - q2 * sn;
  q[base + 32] = q2 * c + q1 * sn;
  float k1 = k[base], k2 = k[base + 32];
  k[base] = k1 * c - k2 * sn;
  k[base + 32] = k2 * c + k1 * sn;
}

// ---------------------------------------------------------------------------
// Causal attention, one block per (query row, head). Scores in LDS.
// ---------------------------------------------------------------------------
__global__ __launch_bounds__(256) void attn_k(const float* __restrict__ q,
                                              const float* __restrict__ k,
                                              const float* __restrict__ v,
                                              float* __restrict__ out) {
  int qi = blockIdx.x;
  int hh = blockIdx.y;
  int tid = threadIdx.x;
  __shared__ float sc[S];
  __shared__ float qv[DH];
  __shared__ float red[256];
  if (tid < DH) qv[tid] = q[(size_t)qi * D + hh * DH + tid];
  __syncthreads();
  int nk = qi + 1;
  const float4* qv4 = (const float4*)qv;
  float lmax = -1e30f;
  for (int kk = tid; kk < nk; kk += 256) {
    const float4* kr = (const float4*)(k + (size_t)kk * D + hh * DH);
    float dot = 0.f;
#pragma unroll
    for (int d4 = 0; d4 < 16; d4++) {
      float4 a = qv4[d4];
      float4 b = kr[d4];
      dot += a.x * b.x + a.y * b.y + a.z * b.z + a.w * b.w;
    }
    dot *= 0.125f;  // 1/sqrt(64)
    sc[kk] = dot;
    lmax = fmaxf(lmax, dot);
  }
  red[tid] = lmax;
  __syncthreads();
  for (int st = 128; st > 0; st >>= 1) {
    if (tid < st) red[tid] = fmaxf(red[tid], red[tid + st]);
    __syncthreads();
  }
  float m = red[0];
  __syncthreads();
  float lsum = 0.f;
  for (int kk = tid; kk < nk; kk += 256) {
    float p = __expf(sc[kk] - m);
    sc[kk] = p;
    lsum += p;
  }
  red[tid] = lsum;
  __syncthreads();
  for (int st = 128; st > 0; st >>= 1) {
    if (tid < st) red[tid] += red[tid + st];
    __syncthreads();
  }
  float denom = red[0];
  __syncthreads();
  // A@V: 4 key-chunks x 64 dims
  int d = tid & 63, c = tid >> 6;
  float acc = 0.f;
  for (int kk = c; kk < nk; kk += 4)
    acc += sc[kk] * v[(size_t)kk * D + hh * DH + d];
  red[tid] = acc;
  __syncthreads();
  if (tid < 64) {
    float r = red[d] + red[64 + d] + red[128 + d] + red[192 + d];
    out[(size_t)qi * D + hh * DH + d] = r / denom;
  }
}

// ---------------------------------------------------------------------------
// MoE gate: logits = x @ gate_w^T (E=8), softmax, top-2 -> comb[s, e]
// ---------------------------------------------------------------------------
__global__ __launch_bounds__(256) void gate_top2_k(const float* __restrict__ x,
                                                   const float* __restrict__ gw,
                                                   float* __restrict__ comb) {
  int s = blockIdx.x, tid = threadIdx.x;
  __shared__ float xs[D];
  __shared__ float red[E][32];
  __shared__ float lg[E];
  for (int i = tid; i < D; i += 256) xs[i] = x[(size_t)s * D + i];
  __syncthreads();
  int e = tid >> 5, j = tid & 31;
  float p = 0.f;
  for (int d = j; d < D; d += 32) p += xs[d] * gw[e * D + d];
  red[e][j] = p;
  __syncthreads();
  if (tid < E) {
    float sum = 0.f;
    for (int jj = 0; jj < 32; jj++) sum += red[tid][jj];
    lg[tid] = sum;
  }
  __syncthreads();
  if (tid == 0) {
    float m = lg[0];
    for (int i = 1; i < E; i++) m = fmaxf(m, lg[i]);
    float pr[E];
    float ssum = 0.f;
    for (int i = 0; i < E; i++) { pr[i] = __expf(lg[i] - m); ssum += pr[i]; }
    float rs = 1.0f / ssum;
    for (int i = 0; i < E; i++) pr[i] *= rs;
    int b1 = 0;
    for (int i = 1; i < E; i++) if (pr[i] > pr[b1]) b1 = i;   // first-on-tie like lax.top_k
    int b2 = -1;
    for (int i = 0; i < E; i++) {
      if (i == b1) continue;
      if (b2 < 0 || pr[i] > pr[b2]) b2 = i;
    }
    for (int i = 0; i < E; i++)
      comb[(size_t)s * E + i] = (i == b1) ? pr[b1] : ((i == b2) ? pr[b2] : 0.f);
  }
}

// act[s,e,i] = silu(g)*u*comb[s,e]   (in-place into g)
__global__ __launch_bounds__(256) void silu_moe_k(float* __restrict__ g,
                                                  const float* __restrict__ u,
                                                  const float* __restrict__ comb) {
  int idx = blockIdx.x * 256 + threadIdx.x;   // S*E*I
  int se = idx >> 9;                          // / I_DIM
  int s = se >> 3, e = se & 7;
  float gv = g[idx];
  float sig = 1.0f / (1.0f + __expf(-gv));
  g[idx] = gv * sig * u[idx] * comb[(size_t)s * E + e];
}

// a = silu(a)*b  (shared expert activation)
__global__ __launch_bounds__(256) void silu2_k(float* __restrict__ a,
                                               const float* __restrict__ b) {
  int idx = blockIdx.x * 256 + threadIdx.x;   // S*SI
  float av = a[idx];
  float sig = 1.0f / (1.0f + __expf(-av));
  a[idx] = av * sig * b[idx];
}

// ---------------------------------------------------------------------------
// Online logsumexp over vocab chunks + target logit capture + final loss
// ---------------------------------------------------------------------------
__global__ __launch_bounds__(256) void init_lse_k(float* m_arr, float* l_arr, float* tgt_l) {
  int i = blockIdx.x * 256 + threadIdx.x;
  if (i < S) { m_arr[i] = -1e30f; l_arr[i] = 0.f; tgt_l[i] = 0.f; }
}

__global__ __launch_bounds__(256) void lse_update_k(const float* __restrict__ logits,
                                                    const int* __restrict__ target,
                                                    float* __restrict__ m_arr,
                                                    float* __restrict__ l_arr,
                                                    float* __restrict__ tgt_l,
                                                    int base, int cn) {
  int s = blockIdx.x, tid = threadIdx.x;
  __shared__ float red[256];
  const float* row = logits + (size_t)s * cn;
  float lm = -1e30f;
  for (int j = tid; j < cn; j += 256) lm = fmaxf(lm, row[j]);
  red[tid] = lm;
  __syncthreads();
  for (int st = 128; st > 0; st >>= 1) {
    if (tid < st) red[tid] = fmaxf(red[tid], red[tid + st]);
    __syncthreads();
  }
  float cm = red[0];
  __syncthreads();
  float ls = 0.f;
  for (int j = tid; j < cn; j += 256) ls += __expf(row[j] - cm);
  red[tid] = ls;
  __syncthreads();
  for (int st = 128; st > 0; st >>= 1) {
    if (tid < st) red[tid] += red[tid + st];
    __syncthreads();
  }
  if (tid == 0) {
    float cs = red[0];
    float m = m_arr[s], l = l_arr[s];
    float nm = fmaxf(m, cm);
    l_arr[s] = l * __expf(m - nm) + cs * __expf(cm - nm);
    m_arr[s] = nm;
    int t = target[s] - base;
    if (t >= 0 && t < cn) tgt_l[s] = row[t];
  }
}

__global__ __launch_bounds__(256) void finalize_k(const float* __restrict__ m_arr,
                                                  const float* __restrict__ l_arr,
                                                  const float* __restrict__ tgt_l,
                                                  const int* __restrict__ target,
                                                  float* __restrict__ out) {
  __shared__ float red[256];
  int tid = threadIdx.x;
  float acc = 0.f;
  for (int s = tid; s < S; s += 256) {
    if (target[s] != -100)
      acc += (logf(l_arr[s]) + m_arr[s]) - tgt_l[s];
  }
  red[tid] = acc;
  __syncthreads();
  for (int st = 128; st > 0; st >>= 1) {
    if (tid < st) red[tid] += red[tid + st];
    __syncthreads();
  }
  if (tid == 0) out[0] = red[0];
}

// ---------------------------------------------------------------------------
static void gemm(const float* A, int lda, const float* B, int ldb, float* C, int ldc,
                 int M, int N, int K, bool acc, hipStream_t stream) {
  dim3 g(N / 64, M / 64);
  if (acc) gemm_bt_k<1, 0><<<g, 256, 0, stream>>>(A, lda, B, ldb, C, ldc, K);
  else     gemm_bt_k<0, 0><<<g, 256, 0, stream>>>(A, lda, B, ldb, C, ldc, K);
}

extern "C" void kernel_launch(void* const* d_in, const int* in_sizes, int n_in,
                              void* d_out, int out_size, void* d_ws, size_t ws_size,
                              hipStream_t stream) {
  const int* src_tokens   = (const int*)d_in[0];
  const int* target       = (const int*)d_in[1];
  const float* embed      = (const float*)d_in[2];
  const float* Wq         = (const float*)d_in[3];
  const float* Wk         = (const float*)d_in[4];
  const float* Wv         = (const float*)d_in[5];
  const float* Wo         = (const float*)d_in[6];
  const float* ln1        = (const float*)d_in[7];
  const float* ln2        = (const float*)d_in[8];
  const float* gate_w     = (const float*)d_in[9];
  const float* gate_projs = (const float*)d_in[10];
  const float* up_projs   = (const float*)d_in[11];
  const float* down_projs = (const float*)d_in[12];
  const float* sg         = (const float*)d_in[13];
  const float* su         = (const float*)d_in[14];
  const float* sd         = (const float*)d_in[15];
  const float* final_ln   = (const float*)d_in[16];
  const float* lm_head    = (const float*)d_in[17];
  float* out = (float*)d_out;

  // Workspace layout (floats). SD = 2M floats = 8 MB. Total ~134.3 MB.
  float* ws = (float*)d_ws;
  const size_t SD = (size_t)S * D;
  float* h     = ws;
  float* x     = ws + SD;
  float* q     = ws + 2 * SD;
  float* k     = ws + 3 * SD;
  float* v     = ws + 4 * SD;
  float* ao    = ws + 5 * SD;
  float* g_all = ws + 6 * SD;    // 4*SD (S x E*I)
  float* u_all = ws + 10 * SD;   // 4*SD
  float* xg    = ws + 14 * SD;
  float* xu    = ws + 15 * SD;
  float* logits = g_all;         // reused after layers (S x 4096 max)
  float* comb  = ws + 16 * SD;
  float* m_arr = comb + (size_t)S * E;
  float* l_arr = m_arr + S;
  float* tgt_l = l_arr + S;

  embed_k<<<(S * D / 4) / 256, 256, 0, stream>>>(src_tokens, embed, h);

  for (int l = 0; l < LAYERS; l++) {
    const float* Wq_l = Wq + (size_t)l * D * D;
    const float* Wk_l = Wk + (size_t)l * D * D;
    const float* Wv_l = Wv + (size_t)l * D * D;
    const float* Wo_l = Wo + (size_t)l * D * D;

    rmsnorm_k<<<S, 256, 0, stream>>>(h, ln1 + (size_t)l * D, x);
    gemm(x, D, Wq_l, D, q, D, S, D, D, false, stream);
    gemm(x, D, Wk_l, D, k, D, S, D, D, false, stream);
    gemm(x, D, Wv_l, D, v, D, S, D, D, false, stream);
    rope_k<<<(S * H * 32) / 256, 256, 0, stream>>>(q, k);
    attn_k<<<dim3(S, H), 256, 0, stream>>>(q, k, v, ao);
    gemm(ao, D, Wo_l, D, h, D, S, D, D, true, stream);  // h += ao @ Wo^T

    rmsnorm_k<<<S, 256, 0, stream>>>(h, ln2 + (size_t)l * D, x);
    gate_top2_k<<<S, 256, 0, stream>>>(x, gate_w + (size_t)l * E * D, comb);
    // dense expert g/u: B reshaped [E*I, D]
    gemm(x, D, gate_projs + (size_t)l * E * I_DIM * D, D, g_all, E * I_DIM,
         S, E * I_DIM, D, false, stream);
    gemm(x, D, up_projs + (size_t)l * E * I_DIM * D, D, u_all, E * I_DIM,
         S, E * I_DIM, D, false, stream);
    silu_moe_k<<<(S * E * I_DIM) / 256, 256, 0, stream>>>(g_all, u_all, comb);
    // all-expert down-projection as one K=E*I GEMM, h += ...
    gemm_bt_k<1, 1><<<dim3(D / 64, S / 64), 256, 0, stream>>>(
        g_all, E * I_DIM, down_projs + (size_t)l * E * D * I_DIM, 0, h, D, E * I_DIM);
    // shared expert
    gemm(x, D, sg + (size_t)l * SI * D, D, xg, SI, S, SI, D, false, stream);
    gemm(x, D, su + (size_t)l * SI * D, D, xu, SI, S, SI, D, false, stream);
    silu2_k<<<(S * SI) / 256, 256, 0, stream>>>(xg, xu);
    gemm(xg, SI, sd + (size_t)l * D * SI, SI, h, D, S, D, SI, true, stream);  // h += t @ sd^T
  }

  rmsnorm_k<<<S, 256, 0, stream>>>(h, final_ln, x);
  init_lse_k<<<(S + 255) / 256, 256, 0, stream>>>(m_arr, l_arr, tgt_l);
  for (int c = 0; c < 8; c++) {
    int base = c * 4096;
    int cn = (c == 7) ? (V - 7 * 4096) : 4096;  // 3328, still /64
    gemm(x, D, lm_head + (size_t)base * D, D, logits, cn, S, cn, D, false, stream);
    lse_update_k<<<S, 256, 0, stream>>>(logits, target, m_arr, l_arr, tgt_l, base, cn);
  }
  finalize_k<<<1, 256, 0, stream>>>(m_arr, l_arr, tgt_l, target, out);
}

// Round 3
// 5208.514 us; speedup vs baseline: 1.6218x; 1.6218x over previous
//
#include <hip/hip_runtime.h>
#include <hip/hip_bf16.h>

// Problem constants (DeepSeek-V2-style scaled config)
#define S 2048
#define D 1024
#define H 16
#define DH 64
#define LAYERS 2
#define E 8
#define I_DIM 512
#define SI 1024
#define V 32000

typedef __attribute__((ext_vector_type(8))) short short8;   // 8 bf16 (4 VGPRs)
typedef __attribute__((ext_vector_type(4))) float floatx4;  // MFMA accumulator

// f32 -> bf16 with round-to-nearest-even
__device__ __forceinline__ unsigned short f2bf(float f) {
  union { float f; unsigned u; } x; x.f = f;
  unsigned r = x.u + 0x7FFFu + ((x.u >> 16) & 1u);
  return (unsigned short)(r >> 16);
}
__device__ __forceinline__ int pack2(float a, float b) {
  return (int)((unsigned)f2bf(a) | ((unsigned)f2bf(b) << 16));
}

// ---------------------------------------------------------------------------
// Embedding lookup
// ---------------------------------------------------------------------------
__global__ __launch_bounds__(256) void embed_k(const int* __restrict__ tok,
                                               const float* __restrict__ emb,
                                               float* __restrict__ h) {
  int idx = blockIdx.x * 256 + threadIdx.x;
  if (idx >= S * D / 4) return;
  int s = idx >> 8;
  int d4 = idx & 255;
  int t = tok[s];
  float4 u = *(const float4*)(emb + (size_t)t * D + d4 * 4);
  *(float4*)(h + (size_t)s * D + d4 * 4) = u;
}

// ---------------------------------------------------------------------------
// RMSNorm
// ---------------------------------------------------------------------------
__global__ __launch_bounds__(256) void rmsnorm_k(const float* __restrict__ h,
                                                 const float* __restrict__ w,
                                                 float* __restrict__ x) {
  int s = blockIdx.x, tid = threadIdx.x;
  __shared__ float red[256];
  float4 hv = *(const float4*)(h + (size_t)s * D + tid * 4);
  red[tid] = hv.x * hv.x + hv.y * hv.y + hv.z * hv.z + hv.w * hv.w;
  __syncthreads();
  for (int st = 128; st > 0; st >>= 1) {
    if (tid < st) red[tid] += red[tid + st];
    __syncthreads();
  }
  float inv = rsqrtf(red[0] * (1.0f / 1024.0f) + 1e-6f);
  float4 wv = *(const float4*)(w + tid * 4);
  float4 o;
  o.x = hv.x * inv * wv.x;
  o.y = hv.y * inv * wv.y;
  o.z = hv.z * inv * wv.z;
  o.w = hv.w * inv * wv.w;
  *(float4*)(x + (size_t)s * D + tid * 4) = o;
}

// ---------------------------------------------------------------------------
// MFMA GEMM: C[M,N](f32) = A[M,K](f32, rounded to bf16) @ B[N,K](f32->bf16)^T
// Tile TM x TN, BK=32, 256 threads = 4 waves (2x2), 16x16x32 bf16 MFMA.
// Wave covers TM/2 x TN/2. ACC: C += result. EXPERT: B = down_projs [E][D][I].
// Fragment layout (m89/m92-verified): lane&15 -> row of A / row of B^T,
// (lane>>4)*8 -> k-offset; C/D: col=lane&15, row=(lane>>4)*4+reg.
// ---------------------------------------------------------------------------
template <int TM, int TN, int ACC, int EXPERT>
__global__ __launch_bounds__(256) void mfma_gemm_k(const float* __restrict__ A, int lda,
                                                   const float* __restrict__ B, int ldb,
                                                   float* __restrict__ C, int ldc, int K) {
  constexpr int WM = TM / 2, WN = TN / 2;
  constexpr int MT = WM / 16, NT = WN / 16;
  __shared__ __align__(16) short As[TM * 32];
  __shared__ __align__(16) short Bs[TN * 32];
  int tid = threadIdx.x;
  int n0 = blockIdx.x * TN, m0 = blockIdx.y * TM;
  int w = tid >> 6, lane = tid & 63;
  int quad = lane >> 4, l16 = lane & 15;
  int wm = (w >> 1) * WM, wn = (w & 1) * WN;

  floatx4 acc[MT][NT];
#pragma unroll
  for (int mi = 0; mi < MT; mi++)
#pragma unroll
    for (int ni = 0; ni < NT; ni++)
      acc[mi][ni] = (floatx4){0.f, 0.f, 0.f, 0.f};

  for (int k0 = 0; k0 < K; k0 += 32) {
    // stage A tile (TM x 32) -> bf16 LDS; chunk = 8 elems = 16B, contiguous
#pragma unroll
    for (int i = 0; i < TM / 64; i++) {
      int c = tid + i * 256;
      int row = c >> 2, ko = (c & 3) * 8;
      const float* p = A + (size_t)(m0 + row) * lda + k0 + ko;
      float4 f0 = *(const float4*)p;
      float4 f1 = *(const float4*)(p + 4);
      int4 pk = {pack2(f0.x, f0.y), pack2(f0.z, f0.w),
                 pack2(f1.x, f1.y), pack2(f1.z, f1.w)};
      ((int4*)As)[c] = pk;
    }
    // stage B tile (TN x 32)
#pragma unroll
    for (int i = 0; i < TN / 64; i++) {
      int c = tid + i * 256;
      int row = c >> 2, ko = (c & 3) * 8;
      const float* p;
      if (EXPERT) {
        int k = k0 + ko;
        int e = k >> 9;
        p = B + ((size_t)(e * D + n0 + row)) * I_DIM + (k & 511);
      } else {
        p = B + (size_t)(n0 + row) * ldb + k0 + ko;
      }
      float4 f0 = *(const float4*)p;
      float4 f1 = *(const float4*)(p + 4);
      int4 pk = {pack2(f0.x, f0.y), pack2(f0.z, f0.w),
                 pack2(f1.x, f1.y), pack2(f1.z, f1.w)};
      ((int4*)Bs)[c] = pk;
    }
    __syncthreads();
    short8 af[MT], bfr[NT];
#pragma unroll
    for (int mi = 0; mi < MT; mi++)
      af[mi] = *(const short8*)(As + (wm + mi * 16 + l16) * 32 + quad * 8);
#pragma unroll
    for (int ni = 0; ni < NT; ni++)
      bfr[ni] = *(const short8*)(Bs + (wn + ni * 16 + l16) * 32 + quad * 8);
#pragma unroll
    for (int mi = 0; mi < MT; mi++)
#pragma unroll
      for (int ni = 0; ni < NT; ni++)
        acc[mi][ni] = __builtin_amdgcn_mfma_f32_16x16x32_bf16(af[mi], bfr[ni],
                                                              acc[mi][ni], 0, 0, 0);
    __syncthreads();
  }
  // epilogue: D col=lane&15, row=quad*4+r
#pragma unroll
  for (int mi = 0; mi < MT; mi++) {
#pragma unroll
    for (int ni = 0; ni < NT; ni++) {
      int row_base = m0 + wm + mi * 16 + quad * 4;
      int col = n0 + wn + ni * 16 + l16;
#pragma unroll
      for (int r = 0; r < 4; r++) {
        float* cp = C + (size_t)(row_base + r) * ldc + col;
        float val = acc[mi][ni][r];
        if (ACC) val += *cp;
        *cp = val;
      }
    }
  }
}

// ---------------------------------------------------------------------------
// RoPE applied in-place to q and k.
// ---------------------------------------------------------------------------
__global__ __launch_bounds__(256) void rope_k(float* __restrict__ q, float* __restrict__ k) {
  int idx = blockIdx.x * 256 + threadIdx.x;   // S*H*32
  int s = idx >> 9;
  int r = idx & 511;
  int hd = r >> 5, i = r & 31;
  float invf = expf(-(float)i * (9.210340371976184f / 32.0f));
  float ang = (float)s * invf;
  float c = cosf(ang), sn = sinf(ang);
  int base = s * D + hd * DH + i;
  float q1 = q[base], q2 = q[base + 32];
  q[base] = q1 * c - q2 * sn;
  q[base + 32] = q2 * c + q1 * sn;
  float k1 = k[base], k2 = k[base + 32];
  k[base] = k1 * c - k2 * sn;
  k[base + 32] = k2 * c + k1 * sn;
}

// ---------------------------------------------------------------------------
// Causal attention, one block per (query row, head). (unchanged this round)
// ---------------------------------------------------------------------------
__global__ __launch_bounds__(256) void attn_k(const float* __restrict__ q,
                                              const float* __restrict__ k,
                                              const float* __restrict__ v,
                                              float* __restrict__ out) {
  int qi = blockIdx.x;
  int hh = blockIdx.y;
  int tid = threadIdx.x;
  __shared__ float sc[S];
  __shared__ float qv[DH];
  __shared__ float red[256];
  if (tid < DH) qv[tid] = q[(size_t)qi * D + hh * DH + tid];
  __syncthreads();
  int nk = qi + 1;
  const float4* qv4 = (const float4*)qv;
  float lmax = -1e30f;
  for (int kk = tid; kk < nk; kk += 256) {
    const float4* kr = (const float4*)(k + (size_t)kk * D + hh * DH);
    float dot = 0.f;
#pragma unroll
    for (int d4 = 0; d4 < 16; d4++) {
      float4 a = qv4[d4];
      float4 b = kr[d4];
      dot += a.x * b.x + a.y * b.y + a.z * b.z + a.w * b.w;
    }
    dot *= 0.125f;
    sc[kk] = dot;
    lmax = fmaxf(lmax, dot);
  }
  red[tid] = lmax;
  __syncthreads();
  for (int st = 128; st > 0; st >>= 1) {
    if (tid < st) red[tid] = fmaxf(red[tid], red[tid + st]);
    __syncthreads();
  }
  float m = red[0];
  __syncthreads();
  float lsum = 0.f;
  for (int kk = tid; kk < nk; kk += 256) {
    float p = __expf(sc[kk] - m);
    sc[kk] = p;
    lsum += p;
  }
  red[tid] = lsum;
  __syncthreads();
  for (int st = 128; st > 0; st >>= 1) {
    if (tid < st) red[tid] += red[tid + st];
    __syncthreads();
  }
  float denom = red[0];
  __syncthreads();
  int d = tid & 63, c = tid >> 6;
  float acc = 0.f;
  for (int kk = c; kk < nk; kk += 4)
    acc += sc[kk] * v[(size_t)kk * D + hh * DH + d];
  red[tid] = acc;
  __syncthreads();
  if (tid < 64) {
    float r = red[d] + red[64 + d] + red[128 + d] + red[192 + d];
    out[(size_t)qi * D + hh * DH + d] = r / denom;
  }
}

// ---------------------------------------------------------------------------
// MoE gate: softmax(x @ gate_w^T), top-2 -> comb[s, e]
// ---------------------------------------------------------------------------
__global__ __launch_bounds__(256) void gate_top2_k(const float* __restrict__ x,
                                                   const float* __restrict__ gw,
                                                   float* __restrict__ comb) {
  int s = blockIdx.x, tid = threadIdx.x;
  __shared__ float xs[D];
  __shared__ float red[E][32];
  __shared__ float lg[E];
  for (int i = tid; i < D; i += 256) xs[i] = x[(size_t)s * D + i];
  __syncthreads();
  int e = tid >> 5, j = tid & 31;
  float p = 0.f;
  for (int d = j; d < D; d += 32) p += xs[d] * gw[e * D + d];
  red[e][j] = p;
  __syncthreads();
  if (tid < E) {
    float sum = 0.f;
    for (int jj = 0; jj < 32; jj++) sum += red[tid][jj];
    lg[tid] = sum;
  }
  __syncthreads();
  if (tid == 0) {
    float m = lg[0];
    for (int i = 1; i < E; i++) m = fmaxf(m, lg[i]);
    float pr[E];
    float ssum = 0.f;
    for (int i = 0; i < E; i++) { pr[i] = __expf(lg[i] - m); ssum += pr[i]; }
    float rs = 1.0f / ssum;
    for (int i = 0; i < E; i++) pr[i] *= rs;
    int b1 = 0;
    for (int i = 1; i < E; i++) if (pr[i] > pr[b1]) b1 = i;
    int b2 = -1;
    for (int i = 0; i < E; i++) {
      if (i == b1) continue;
      if (b2 < 0 || pr[i] > pr[b2]) b2 = i;
    }
    for (int i = 0; i < E; i++)
      comb[(size_t)s * E + i] = (i == b1) ? pr[b1] : ((i == b2) ? pr[b2] : 0.f);
  }
}

__global__ __launch_bounds__(256) void silu_moe_k(float* __restrict__ g,
                                                  const float* __restrict__ u,
                                                  const float* __restrict__ comb) {
  int idx = blockIdx.x * 256 + threadIdx.x;   // S*E*I
  int se = idx >> 9;
  int s = se >> 3, e = se & 7;
  float gv = g[idx];
  float sig = 1.0f / (1.0f + __expf(-gv));
  g[idx] = gv * sig * u[idx] * comb[(size_t)s * E + e];
}

__global__ __launch_bounds__(256) void silu2_k(float* __restrict__ a,
                                               const float* __restrict__ b) {
  int idx = blockIdx.x * 256 + threadIdx.x;   // S*SI
  float av = a[idx];
  float sig = 1.0f / (1.0f + __expf(-av));
  a[idx] = av * sig * b[idx];
}

// ---------------------------------------------------------------------------
// Online logsumexp over vocab chunks + final loss
// ---------------------------------------------------------------------------
__global__ __launch_bounds__(256) void init_lse_k(float* m_arr, float* l_arr, float* tgt_l) {
  int i = blockIdx.x * 256 + threadIdx.x;
  if (i < S) { m_arr[i] = -1e30f; l_arr[i] = 0.f; tgt_l[i] = 0.f; }
}

__global__ __launch_bounds__(256) void lse_update_k(const float* __restrict__ logits,
                                                    const int* __restrict__ target,
                                                    float* __restrict__ m_arr,
                                                    float* __restrict__ l_arr,
                                                    float* __restrict__ tgt_l,
                                                    int base, int cn) {
  int s = blockIdx.x, tid = threadIdx.x;
  __shared__ float red[256];
  const float* row = logits + (size_t)s * cn;
  float lm = -1e30f;
  for (int j = tid; j < cn; j += 256) lm = fmaxf(lm, row[j]);
  red[tid] = lm;
  __syncthreads();
  for (int st = 128; st > 0; st >>= 1) {
    if (tid < st) red[tid] = fmaxf(red[tid], red[tid + st]);
    __syncthreads();
  }
  float cm = red[0];
  __syncthreads();
  float ls = 0.f;
  for (int j = tid; j < cn; j += 256) ls += __expf(row[j] - cm);
  red[tid] = ls;
  __syncthreads();
  for (int st = 128; st > 0; st >>= 1) {
    if (tid < st) red[tid] += red[tid + st];
    __syncthreads();
  }
  if (tid == 0) {
    float cs = red[0];
    float m = m_arr[s], l = l_arr[s];
    float nm = fmaxf(m, cm);
    l_arr[s] = l * __expf(m - nm) + cs * __expf(cm - nm);
    m_arr[s] = nm;
    int t = target[s] - base;
    if (t >= 0 && t < cn) tgt_l[s] = row[t];
  }
}

__global__ __launch_bounds__(256) void finalize_k(const float* __restrict__ m_arr,
                                                  const float* __restrict__ l_arr,
                                                  const float* __restrict__ tgt_l,
                                                  const int* __restrict__ target,
                                                  float* __restrict__ out) {
  __shared__ float red[256];
  int tid = threadIdx.x;
  float acc = 0.f;
  for (int s = tid; s < S; s += 256) {
    if (target[s] != -100)
      acc += (logf(l_arr[s]) + m_arr[s]) - tgt_l[s];
  }
  red[tid] = acc;
  __syncthreads();
  for (int st = 128; st > 0; st >>= 1) {
    if (tid < st) red[tid] += red[tid + st];
    __syncthreads();
  }
  if (tid == 0) out[0] = red[0];
}

// ---------------------------------------------------------------------------
// GEMM dispatch: N>=2048 -> 128x128 tile; else 64x128 (full CU coverage).
// ---------------------------------------------------------------------------
static void gemm(const float* A, int lda, const float* B, int ldb, float* C, int ldc,
                 int M, int N, int K, bool acc, hipStream_t stream) {
  if (N >= 2048) {
    dim3 g(N / 128, M / 128);
    if (acc) mfma_gemm_k<128, 128, 1, 0><<<g, 256, 0, stream>>>(A, lda, B, ldb, C, ldc, K);
    else     mfma_gemm_k<128, 128, 0, 0><<<g, 256, 0, stream>>>(A, lda, B, ldb, C, ldc, K);
  } else {
    dim3 g(N / 128, M / 64);
    if (acc) mfma_gemm_k<64, 128, 1, 0><<<g, 256, 0, stream>>>(A, lda, B, ldb, C, ldc, K);
    else     mfma_gemm_k<64, 128, 0, 0><<<g, 256, 0, stream>>>(A, lda, B, ldb, C, ldc, K);
  }
}

extern "C" void kernel_launch(void* const* d_in, const int* in_sizes, int n_in,
                              void* d_out, int out_size, void* d_ws, size_t ws_size,
                              hipStream_t stream) {
  const int* src_tokens   = (const int*)d_in[0];
  const int* target       = (const int*)d_in[1];
  const float* embed      = (const float*)d_in[2];
  const float* Wq         = (const float*)d_in[3];
  const float* Wk         = (const float*)d_in[4];
  const float* Wv         = (const float*)d_in[5];
  const float* Wo         = (const float*)d_in[6];
  const float* ln1        = (const float*)d_in[7];
  const float* ln2        = (const float*)d_in[8];
  const float* gate_w     = (const float*)d_in[9];
  const float* gate_projs = (const float*)d_in[10];
  const float* up_projs   = (const float*)d_in[11];
  const float* down_projs = (const float*)d_in[12];
  const float* sg         = (const float*)d_in[13];
  const float* su         = (const float*)d_in[14];
  const float* sd         = (const float*)d_in[15];
  const float* final_ln   = (const float*)d_in[16];
  const float* lm_head    = (const float*)d_in[17];
  float* out = (float*)d_out;

  float* ws = (float*)d_ws;
  const size_t SD = (size_t)S * D;
  float* h     = ws;
  float* x     = ws + SD;
  float* q     = ws + 2 * SD;
  float* k     = ws + 3 * SD;
  float* v     = ws + 4 * SD;
  float* ao    = ws + 5 * SD;
  float* g_all = ws + 6 * SD;    // S x 4096
  float* u_all = ws + 10 * SD;   // S x 4096
  float* xg    = ws + 14 * SD;
  float* xu    = ws + 15 * SD;
  float* logits = g_all;         // reused after layers
  float* comb  = ws + 16 * SD;
  float* m_arr = comb + (size_t)S * E;
  float* l_arr = m_arr + S;
  float* tgt_l = l_arr + S;

  embed_k<<<(S * D / 4) / 256, 256, 0, stream>>>(src_tokens, embed, h);

  for (int l = 0; l < LAYERS; l++) {
    const float* Wq_l = Wq + (size_t)l * D * D;
    const float* Wk_l = Wk + (size_t)l * D * D;
    const float* Wv_l = Wv + (size_t)l * D * D;
    const float* Wo_l = Wo + (size_t)l * D * D;

    rmsnorm_k<<<S, 256, 0, stream>>>(h, ln1 + (size_t)l * D, x);
    gemm(x, D, Wq_l, D, q, D, S, D, D, false, stream);
    gemm(x, D, Wk_l, D, k, D, S, D, D, false, stream);
    gemm(x, D, Wv_l, D, v, D, S, D, D, false, stream);
    rope_k<<<(S * H * 32) / 256, 256, 0, stream>>>(q, k);
    attn_k<<<dim3(S, H), 256, 0, stream>>>(q, k, v, ao);
    gemm(ao, D, Wo_l, D, h, D, S, D, D, true, stream);  // h += ao @ Wo^T

    rmsnorm_k<<<S, 256, 0, stream>>>(h, ln2 + (size_t)l * D, x);
    gate_top2_k<<<S, 256, 0, stream>>>(x, gate_w + (size_t)l * E * D, comb);
    gemm(x, D, gate_projs + (size_t)l * E * I_DIM * D, D, g_all, E * I_DIM,
         S, E * I_DIM, D, false, stream);
    gemm(x, D, up_projs + (size_t)l * E * I_DIM * D, D, u_all, E * I_DIM,
         S, E * I_DIM, D, false, stream);
    silu_moe_k<<<(S * E * I_DIM) / 256, 256, 0, stream>>>(g_all, u_all, comb);
    // all-expert down-projection (K = E*I = 4096), h += ...
    mfma_gemm_k<64, 128, 1, 1><<<dim3(D / 128, S / 64), 256, 0, stream>>>(
        g_all, E * I_DIM, down_projs + (size_t)l * E * D * I_DIM, 0, h, D, E * I_DIM);
    // shared expert
    gemm(x, D, sg + (size_t)l * SI * D, D, xg, SI, S, SI, D, false, stream);
    gemm(x, D, su + (size_t)l * SI * D, D, xu, SI, S, SI, D, false, stream);
    silu2_k<<<(S * SI) / 256, 256, 0, stream>>>(xg, xu);
    gemm(xg, SI, sd + (size_t)l * D * SI, SI, h, D, S, D, SI, true, stream);  // h += t @ sd^T
  }

  rmsnorm_k<<<S, 256, 0, stream>>>(h, final_ln, x);
  init_lse_k<<<(S + 255) / 256, 256, 0, stream>>>(m_arr, l_arr, tgt_l);
  for (int c = 0; c < 8; c++) {
    int base = c * 4096;
    int cn = (c == 7) ? (V - 7 * 4096) : 4096;  // 3328 = 26*128
    gemm(x, D, lm_head + (size_t)base * D, D, logits, cn, S, cn, D, false, stream);
    lse_update_k<<<S, 256, 0, stream>>>(logits, target, m_arr, l_arr, tgt_l, base, cn);
  }
  finalize_k<<<1, 256, 0, stream>>>(m_arr, l_arr, tgt_l, target, out);
}

// Round 4
// 2126.583 us; speedup vs baseline: 3.9721x; 2.4492x over previous
//
#include <hip/hip_runtime.h>
#include <hip/hip_bf16.h>

// Problem constants (DeepSeek-V2-style scaled config)
#define S 2048
#define D 1024
#define H 16
#define DH 64
#define LAYERS 2
#define E 8
#define I_DIM 512
#define SI 1024
#define V 32000

typedef __attribute__((ext_vector_type(8))) short short8;   // 8 bf16 (4 VGPRs)
typedef __attribute__((ext_vector_type(4))) float floatx4;  // MFMA accumulator

// f32 -> bf16 with round-to-nearest-even
__device__ __forceinline__ unsigned short f2bf(float f) {
  union { float f; unsigned u; } x; x.f = f;
  unsigned r = x.u + 0x7FFFu + ((x.u >> 16) & 1u);
  return (unsigned short)(r >> 16);
}
__device__ __forceinline__ int pack2(float a, float b) {
  return (int)((unsigned)f2bf(a) | ((unsigned)f2bf(b) << 16));
}

// ---------------------------------------------------------------------------
// Embedding lookup
// ---------------------------------------------------------------------------
__global__ __launch_bounds__(256) void embed_k(const int* __restrict__ tok,
                                               const float* __restrict__ emb,
                                               float* __restrict__ h) {
  int idx = blockIdx.x * 256 + threadIdx.x;
  if (idx >= S * D / 4) return;
  int s = idx >> 8;
  int d4 = idx & 255;
  int t = tok[s];
  float4 u = *(const float4*)(emb + (size_t)t * D + d4 * 4);
  *(float4*)(h + (size_t)s * D + d4 * 4) = u;
}

// ---------------------------------------------------------------------------
// RMSNorm
// ---------------------------------------------------------------------------
__global__ __launch_bounds__(256) void rmsnorm_k(const float* __restrict__ h,
                                                 const float* __restrict__ w,
                                                 float* __restrict__ x) {
  int s = blockIdx.x, tid = threadIdx.x;
  __shared__ float red[256];
  float4 hv = *(const float4*)(h + (size_t)s * D + tid * 4);
  red[tid] = hv.x * hv.x + hv.y * hv.y + hv.z * hv.z + hv.w * hv.w;
  __syncthreads();
  for (int st = 128; st > 0; st >>= 1) {
    if (tid < st) red[tid] += red[tid + st];
    __syncthreads();
  }
  float inv = rsqrtf(red[0] * (1.0f / 1024.0f) + 1e-6f);
  float4 wv = *(const float4*)(w + tid * 4);
  float4 o;
  o.x = hv.x * inv * wv.x;
  o.y = hv.y * inv * wv.y;
  o.z = hv.z * inv * wv.z;
  o.w = hv.w * inv * wv.w;
  *(float4*)(x + (size_t)s * D + tid * 4) = o;
}

// ---------------------------------------------------------------------------
// MFMA GEMM: C[M,N](f32) = A[M,K](f32->bf16) @ B[N,K](f32->bf16)^T
// Tile TM x TN, BK=32, 256 threads = 4 waves (2x2), 16x16x32 bf16 MFMA.
// ---------------------------------------------------------------------------
template <int TM, int TN, int ACC, int EXPERT>
__global__ __launch_bounds__(256) void mfma_gemm_k(const float* __restrict__ A, int lda,
                                                   const float* __restrict__ B, int ldb,
                                                   float* __restrict__ C, int ldc, int K) {
  constexpr int WM = TM / 2, WN = TN / 2;
  constexpr int MT = WM / 16, NT = WN / 16;
  __shared__ __align__(16) short As[TM * 32];
  __shared__ __align__(16) short Bs[TN * 32];
  int tid = threadIdx.x;
  int n0 = blockIdx.x * TN, m0 = blockIdx.y * TM;
  int w = tid >> 6, lane = tid & 63;
  int quad = lane >> 4, l16 = lane & 15;
  int wm = (w >> 1) * WM, wn = (w & 1) * WN;

  floatx4 acc[MT][NT];
#pragma unroll
  for (int mi = 0; mi < MT; mi++)
#pragma unroll
    for (int ni = 0; ni < NT; ni++)
      acc[mi][ni] = (floatx4){0.f, 0.f, 0.f, 0.f};

  for (int k0 = 0; k0 < K; k0 += 32) {
#pragma unroll
    for (int i = 0; i < TM / 64; i++) {
      int c = tid + i * 256;
      int row = c >> 2, ko = (c & 3) * 8;
      const float* p = A + (size_t)(m0 + row) * lda + k0 + ko;
      float4 f0 = *(const float4*)p;
      float4 f1 = *(const float4*)(p + 4);
      int4 pk = {pack2(f0.x, f0.y), pack2(f0.z, f0.w),
                 pack2(f1.x, f1.y), pack2(f1.z, f1.w)};
      ((int4*)As)[c] = pk;
    }
#pragma unroll
    for (int i = 0; i < TN / 64; i++) {
      int c = tid + i * 256;
      int row = c >> 2, ko = (c & 3) * 8;
      const float* p;
      if (EXPERT) {
        int k = k0 + ko;
        int e = k >> 9;
        p = B + ((size_t)(e * D + n0 + row)) * I_DIM + (k & 511);
      } else {
        p = B + (size_t)(n0 + row) * ldb + k0 + ko;
      }
      float4 f0 = *(const float4*)p;
      float4 f1 = *(const float4*)(p + 4);
      int4 pk = {pack2(f0.x, f0.y), pack2(f0.z, f0.w),
                 pack2(f1.x, f1.y), pack2(f1.z, f1.w)};
      ((int4*)Bs)[c] = pk;
    }
    __syncthreads();
    short8 af[MT], bfr[NT];
#pragma unroll
    for (int mi = 0; mi < MT; mi++)
      af[mi] = *(const short8*)(As + (wm + mi * 16 + l16) * 32 + quad * 8);
#pragma unroll
    for (int ni = 0; ni < NT; ni++)
      bfr[ni] = *(const short8*)(Bs + (wn + ni * 16 + l16) * 32 + quad * 8);
#pragma unroll
    for (int mi = 0; mi < MT; mi++)
#pragma unroll
      for (int ni = 0; ni < NT; ni++)
        acc[mi][ni] = __builtin_amdgcn_mfma_f32_16x16x32_bf16(af[mi], bfr[ni],
                                                              acc[mi][ni], 0, 0, 0);
    __syncthreads();
  }
#pragma unroll
  for (int mi = 0; mi < MT; mi++) {
#pragma unroll
    for (int ni = 0; ni < NT; ni++) {
      int row_base = m0 + wm + mi * 16 + quad * 4;
      int col = n0 + wn + ni * 16 + l16;
#pragma unroll
      for (int r = 0; r < 4; r++) {
        float* cp = C + (size_t)(row_base + r) * ldc + col;
        float val = acc[mi][ni][r];
        if (ACC) val += *cp;
        *cp = val;
      }
    }
  }
}

// ---------------------------------------------------------------------------
// RoPE applied in-place to q and k.
// ---------------------------------------------------------------------------
__global__ __launch_bounds__(256) void rope_k(float* __restrict__ q, float* __restrict__ k) {
  int idx = blockIdx.x * 256 + threadIdx.x;   // S*H*32
  int s = idx >> 9;
  int r = idx & 511;
  int hd = r >> 5, i = r & 31;
  float invf = expf(-(float)i * (9.210340371976184f / 32.0f));
  float ang = (float)s * invf;
  float c = cosf(ang), sn = sinf(ang);
  int base = s * D + hd * DH + i;
  float q1 = q[base], q2 = q[base + 32];
  q[base] = q1 * c - q2 * sn;
  q[base + 32] = q2 * c + q1 * sn;
  float k1 = k[base], k2 = k[base + 32];
  k[base] = k1 * c - k2 * sn;
  k[base + 32] = k2 * c + k1 * sn;
}

// ---------------------------------------------------------------------------
// Flash attention (MFMA). One block per (64-query tile, head); 4 waves.
// Wave w owns query rows [w*16, w*16+16) of the tile -> softmax stats are
// in-wave (shfl over 16-lane groups). K-tiles of 64 keys: stage K (rows=key)
// and V^T (rows=d) as bf16 in LDS, QK^T -> online softmax -> P via wave-
// private LDS strip (C-layout -> A-layout) -> PV. Stride 72 shorts keeps
// 16B alignment for ds_read_b128 and 2-way-max bank aliasing.
// ---------------------------------------------------------------------------
#define PSTR 72
__global__ __launch_bounds__(256) void flash_attn_k(const float* __restrict__ q,
                                                    const float* __restrict__ k,
                                                    const float* __restrict__ v,
                                                    float* __restrict__ out) {
  __shared__ __align__(16) short QPs[64 * PSTR];  // Q tile, then per-wave P strips
  __shared__ __align__(16) short Ks[64 * PSTR];
  __shared__ __align__(16) short Vt[64 * PSTR];
  int qt = blockIdx.x, hh = blockIdx.y;
  int q0 = qt * 64;
  int tid = threadIdx.x;
  int w = tid >> 6, lane = tid & 63, quad = lane >> 4, l16 = lane & 15;

  // stage Q tile (64 x 64) as bf16
  {
    int row = tid >> 2, c0 = (tid & 3) * 16;
    const float* p = q + (size_t)(q0 + row) * D + hh * DH + c0;
    float4 f0 = ((const float4*)p)[0], f1 = ((const float4*)p)[1];
    float4 f2 = ((const float4*)p)[2], f3 = ((const float4*)p)[3];
    int4 pk0 = {pack2(f0.x, f0.y), pack2(f0.z, f0.w), pack2(f1.x, f1.y), pack2(f1.z, f1.w)};
    int4 pk1 = {pack2(f2.x, f2.y), pack2(f2.z, f2.w), pack2(f3.x, f3.y), pack2(f3.z, f3.w)};
    *(int4*)(QPs + row * PSTR + c0) = pk0;
    *(int4*)(QPs + row * PSTR + c0 + 8) = pk1;
  }
  __syncthreads();
  short8 af[2];
  af[0] = *(const short8*)(QPs + (w * 16 + l16) * PSTR + quad * 8);
  af[1] = *(const short8*)(QPs + (w * 16 + l16) * PSTR + 32 + quad * 8);

  float m_i[4], l_i[4];
  floatx4 oacc[4];
#pragma unroll
  for (int r = 0; r < 4; r++) { m_i[r] = -1e30f; l_i[r] = 0.f; }
#pragma unroll
  for (int ni = 0; ni < 4; ni++) oacc[ni] = (floatx4){0.f, 0.f, 0.f, 0.f};

  for (int kt = 0; kt <= qt; kt++) {
    int kb = kt * 64;
    __syncthreads();  // all waves done reading Ks/Vt from previous tile
    // stage K tile (rows = key, cols = d)
    {
      int row = tid >> 2, c0 = (tid & 3) * 16;
      const float* p = k + (size_t)(kb + row) * D + hh * DH + c0;
      float4 f0 = ((const float4*)p)[0], f1 = ((const float4*)p)[1];
      float4 f2 = ((const float4*)p)[2], f3 = ((const float4*)p)[3];
      int4 pk0 = {pack2(f0.x, f0.y), pack2(f0.z, f0.w), pack2(f1.x, f1.y), pack2(f1.z, f1.w)};
      int4 pk1 = {pack2(f2.x, f2.y), pack2(f2.z, f2.w), pack2(f3.x, f3.y), pack2(f3.z, f3.w)};
      *(int4*)(Ks + row * PSTR + c0) = pk0;
      *(int4*)(Ks + row * PSTR + c0 + 8) = pk1;
    }
    // stage V^T: wave w covers d in [w*16, w*16+16), lane = key
    {
      const float* p = v + (size_t)(kb + lane) * D + hh * DH + w * 16;
      float4 f0 = ((const float4*)p)[0], f1 = ((const float4*)p)[1];
      float4 f2 = ((const float4*)p)[2], f3 = ((const float4*)p)[3];
      float vals[16] = {f0.x, f0.y, f0.z, f0.w, f1.x, f1.y, f1.z, f1.w,
                        f2.x, f2.y, f2.z, f2.w, f3.x, f3.y, f3.z, f3.w};
#pragma unroll
      for (int j = 0; j < 16; j++)
        Vt[(w * 16 + j) * PSTR + lane] = f2bf(vals[j]);
    }
    __syncthreads();
    // S = Q @ K^T for this wave's 16 rows x 64 keys
    floatx4 sfr[4];
#pragma unroll
    for (int ni = 0; ni < 4; ni++) sfr[ni] = (floatx4){0.f, 0.f, 0.f, 0.f};
#pragma unroll
    for (int ks = 0; ks < 2; ks++) {
#pragma unroll
      for (int ni = 0; ni < 4; ni++) {
        short8 bfr = *(const short8*)(Ks + (ni * 16 + l16) * PSTR + ks * 32 + quad * 8);
        sfr[ni] = __builtin_amdgcn_mfma_f32_16x16x32_bf16(af[ks], bfr, sfr[ni], 0, 0, 0);
      }
    }
    // scale + causal mask (only diagonal tile needs it)
    int qrow = q0 + w * 16 + quad * 4;
#pragma unroll
    for (int ni = 0; ni < 4; ni++) {
#pragma unroll
      for (int r = 0; r < 4; r++) {
        float s = sfr[ni][r] * 0.125f;
        if (kt == qt) {
          int key = kb + ni * 16 + l16;
          if (key > qrow + r) s = -1e30f;
        }
        sfr[ni][r] = s;
      }
    }
    // row max (over 4 ni regs + 16 lanes of the l16 group)
    float tmax[4];
#pragma unroll
    for (int r = 0; r < 4; r++)
      tmax[r] = fmaxf(fmaxf(sfr[0][r], sfr[1][r]), fmaxf(sfr[2][r], sfr[3][r]));
#pragma unroll
    for (int msk = 1; msk <= 8; msk <<= 1)
#pragma unroll
      for (int r = 0; r < 4; r++)
        tmax[r] = fmaxf(tmax[r], __shfl_xor(tmax[r], msk));
    float alpha[4];
#pragma unroll
    for (int r = 0; r < 4; r++) {
      float mn = fmaxf(m_i[r], tmax[r]);
      alpha[r] = __expf(m_i[r] - mn);
      m_i[r] = mn;
    }
    // P = exp(S - m), row sums
    float tsum[4] = {0.f, 0.f, 0.f, 0.f};
#pragma unroll
    for (int ni = 0; ni < 4; ni++) {
#pragma unroll
      for (int r = 0; r < 4; r++) {
        float p = __expf(sfr[ni][r] - m_i[r]);
        sfr[ni][r] = p;
        tsum[r] += p;
      }
    }
#pragma unroll
    for (int msk = 1; msk <= 8; msk <<= 1)
#pragma unroll
      for (int r = 0; r < 4; r++)
        tsum[r] += __shfl_xor(tsum[r], msk);
#pragma unroll
    for (int r = 0; r < 4; r++) l_i[r] = l_i[r] * alpha[r] + tsum[r];
    // rescale O accumulator
#pragma unroll
    for (int ni = 0; ni < 4; ni++)
#pragma unroll
      for (int r = 0; r < 4; r++) oacc[ni][r] *= alpha[r];
    // P (C-layout) -> wave-private LDS strip (A-layout rows)
#pragma unroll
    for (int ni = 0; ni < 4; ni++)
#pragma unroll
      for (int r = 0; r < 4; r++)
        QPs[(w * 16 + quad * 4 + r) * PSTR + ni * 16 + l16] = f2bf(sfr[ni][r]);
    __threadfence_block();  // drain LDS writes before same-wave A-frag reads
    // O += P @ V
#pragma unroll
    for (int ks = 0; ks < 2; ks++) {
      short8 pf = *(const short8*)(QPs + (w * 16 + l16) * PSTR + ks * 32 + quad * 8);
#pragma unroll
      for (int ni = 0; ni < 4; ni++) {
        short8 bfr = *(const short8*)(Vt + (ni * 16 + l16) * PSTR + ks * 32 + quad * 8);
        oacc[ni] = __builtin_amdgcn_mfma_f32_16x16x32_bf16(pf, bfr, oacc[ni], 0, 0, 0);
      }
    }
  }
  // epilogue: O / l
#pragma unroll
  for (int r = 0; r < 4; r++) l_i[r] = 1.0f / l_i[r];
#pragma unroll
  for (int ni = 0; ni < 4; ni++) {
#pragma unroll
    for (int r = 0; r < 4; r++) {
      int row = q0 + w * 16 + quad * 4 + r;
      out[(size_t)row * D + hh * DH + ni * 16 + l16] = oacc[ni][r] * l_i[r];
    }
  }
}

// ---------------------------------------------------------------------------
// MoE gate: softmax(x @ gate_w^T), top-2 -> comb[s, e]
// ---------------------------------------------------------------------------
__global__ __launch_bounds__(256) void gate_top2_k(const float* __restrict__ x,
                                                   const float* __restrict__ gw,
                                                   float* __restrict__ comb) {
  int s = blockIdx.x, tid = threadIdx.x;
  __shared__ float xs[D];
  __shared__ float red[E][32];
  __shared__ float lg[E];
  for (int i = tid; i < D; i += 256) xs[i] = x[(size_t)s * D + i];
  __syncthreads();
  int e = tid >> 5, j = tid & 31;
  float p = 0.f;
  for (int d = j; d < D; d += 32) p += xs[d] * gw[e * D + d];
  red[e][j] = p;
  __syncthreads();
  if (tid < E) {
    float sum = 0.f;
    for (int jj = 0; jj < 32; jj++) sum += red[tid][jj];
    lg[tid] = sum;
  }
  __syncthreads();
  if (tid == 0) {
    float m = lg[0];
    for (int i = 1; i < E; i++) m = fmaxf(m, lg[i]);
    float pr[E];
    float ssum = 0.f;
    for (int i = 0; i < E; i++) { pr[i] = __expf(lg[i] - m); ssum += pr[i]; }
    float rs = 1.0f / ssum;
    for (int i = 0; i < E; i++) pr[i] *= rs;
    int b1 = 0;
    for (int i = 1; i < E; i++) if (pr[i] > pr[b1]) b1 = i;
    int b2 = -1;
    for (int i = 0; i < E; i++) {
      if (i == b1) continue;
      if (b2 < 0 || pr[i] > pr[b2]) b2 = i;
    }
    for (int i = 0; i < E; i++)
      comb[(size_t)s * E + i] = (i == b1) ? pr[b1] : ((i == b2) ? pr[b2] : 0.f);
  }
}

__global__ __launch_bounds__(256) void silu_moe_k(float* __restrict__ g,
                                                  const float* __restrict__ u,
                                                  const float* __restrict__ comb) {
  int idx = blockIdx.x * 256 + threadIdx.x;   // S*E*I
  int se = idx >> 9;
  int s = se >> 3, e = se & 7;
  float gv = g[idx];
  float sig = 1.0f / (1.0f + __expf(-gv));
  g[idx] = gv * sig * u[idx] * comb[(size_t)s * E + e];
}

__global__ __launch_bounds__(256) void silu2_k(float* __restrict__ a,
                                               const float* __restrict__ b) {
  int idx = blockIdx.x * 256 + threadIdx.x;   // S*SI
  float av = a[idx];
  float sig = 1.0f / (1.0f + __expf(-av));
  a[idx] = av * sig * b[idx];
}

// ---------------------------------------------------------------------------
// Online logsumexp over vocab chunks + final loss
// ---------------------------------------------------------------------------
__global__ __launch_bounds__(256) void init_lse_k(float* m_arr, float* l_arr, float* tgt_l) {
  int i = blockIdx.x * 256 + threadIdx.x;
  if (i < S) { m_arr[i] = -1e30f; l_arr[i] = 0.f; tgt_l[i] = 0.f; }
}

__global__ __launch_bounds__(256) void lse_update_k(const float* __restrict__ logits,
                                                    const int* __restrict__ target,
                                                    float* __restrict__ m_arr,
                                                    float* __restrict__ l_arr,
                                                    float* __restrict__ tgt_l,
                                                    int base, int cn) {
  int s = blockIdx.x, tid = threadIdx.x;
  __shared__ float red[256];
  const float* row = logits + (size_t)s * cn;
  float lm = -1e30f;
  for (int j = tid; j < cn; j += 256) lm = fmaxf(lm, row[j]);
  red[tid] = lm;
  __syncthreads();
  for (int st = 128; st > 0; st >>= 1) {
    if (tid < st) red[tid] = fmaxf(red[tid], red[tid + st]);
    __syncthreads();
  }
  float cm = red[0];
  __syncthreads();
  float ls = 0.f;
  for (int j = tid; j < cn; j += 256) ls += __expf(row[j] - cm);
  red[tid] = ls;
  __syncthreads();
  for (int st = 128; st > 0; st >>= 1) {
    if (tid < st) red[tid] += red[tid + st];
    __syncthreads();
  }
  if (tid == 0) {
    float cs = red[0];
    float m = m_arr[s], l = l_arr[s];
    float nm = fmaxf(m, cm);
    l_arr[s] = l * __expf(m - nm) + cs * __expf(cm - nm);
    m_arr[s] = nm;
    int t = target[s] - base;
    if (t >= 0 && t < cn) tgt_l[s] = row[t];
  }
}

__global__ __launch_bounds__(256) void finalize_k(const float* __restrict__ m_arr,
                                                  const float* __restrict__ l_arr,
                                                  const float* __restrict__ tgt_l,
                                                  const int* __restrict__ target,
                                                  float* __restrict__ out) {
  __shared__ float red[256];
  int tid = threadIdx.x;
  float acc = 0.f;
  for (int s = tid; s < S; s += 256) {
    if (target[s] != -100)
      acc += (logf(l_arr[s]) + m_arr[s]) - tgt_l[s];
  }
  red[tid] = acc;
  __syncthreads();
  for (int st = 128; st > 0; st >>= 1) {
    if (tid < st) red[tid] += red[tid + st];
    __syncthreads();
  }
  if (tid == 0) out[0] = red[0];
}

// ---------------------------------------------------------------------------
static void gemm(const float* A, int lda, const float* B, int ldb, float* C, int ldc,
                 int M, int N, int K, bool acc, hipStream_t stream) {
  if (N >= 2048) {
    dim3 g(N / 128, M / 128);
    if (acc) mfma_gemm_k<128, 128, 1, 0><<<g, 256, 0, stream>>>(A, lda, B, ldb, C, ldc, K);
    else     mfma_gemm_k<128, 128, 0, 0><<<g, 256, 0, stream>>>(A, lda, B, ldb, C, ldc, K);
  } else {
    dim3 g(N / 128, M / 64);
    if (acc) mfma_gemm_k<64, 128, 1, 0><<<g, 256, 0, stream>>>(A, lda, B, ldb, C, ldc, K);
    else     mfma_gemm_k<64, 128, 0, 0><<<g, 256, 0, stream>>>(A, lda, B, ldb, C, ldc, K);
  }
}

extern "C" void kernel_launch(void* const* d_in, const int* in_sizes, int n_in,
                              void* d_out, int out_size, void* d_ws, size_t ws_size,
                              hipStream_t stream) {
  const int* src_tokens   = (const int*)d_in[0];
  const int* target       = (const int*)d_in[1];
  const float* embed      = (const float*)d_in[2];
  const float* Wq         = (const float*)d_in[3];
  const float* Wk         = (const float*)d_in[4];
  const float* Wv         = (const float*)d_in[5];
  const float* Wo         = (const float*)d_in[6];
  const float* ln1        = (const float*)d_in[7];
  const float* ln2        = (const float*)d_in[8];
  const float* gate_w     = (const float*)d_in[9];
  const float* gate_projs = (const float*)d_in[10];
  const float* up_projs   = (const float*)d_in[11];
  const float* down_projs = (const float*)d_in[12];
  const float* sg         = (const float*)d_in[13];
  const float* su         = (const float*)d_in[14];
  const float* sd         = (const float*)d_in[15];
  const float* final_ln   = (const float*)d_in[16];
  const float* lm_head    = (const float*)d_in[17];
  float* out = (float*)d_out;

  float* ws = (float*)d_ws;
  const size_t SD = (size_t)S * D;
  float* h     = ws;
  float* x     = ws + SD;
  float* q     = ws + 2 * SD;
  float* k     = ws + 3 * SD;
  float* v     = ws + 4 * SD;
  float* ao    = ws + 5 * SD;
  float* g_all = ws + 6 * SD;    // S x 4096
  float* u_all = ws + 10 * SD;   // S x 4096
  float* xg    = ws + 14 * SD;
  float* xu    = ws + 15 * SD;
  float* logits = g_all;         // reused after layers
  float* comb  = ws + 16 * SD;
  float* m_arr = comb + (size_t)S * E;
  float* l_arr = m_arr + S;
  float* tgt_l = l_arr + S;

  embed_k<<<(S * D / 4) / 256, 256, 0, stream>>>(src_tokens, embed, h);

  for (int l = 0; l < LAYERS; l++) {
    const float* Wq_l = Wq + (size_t)l * D * D;
    const float* Wk_l = Wk + (size_t)l * D * D;
    const float* Wv_l = Wv + (size_t)l * D * D;
    const float* Wo_l = Wo + (size_t)l * D * D;

    rmsnorm_k<<<S, 256, 0, stream>>>(h, ln1 + (size_t)l * D, x);
    gemm(x, D, Wq_l, D, q, D, S, D, D, false, stream);
    gemm(x, D, Wk_l, D, k, D, S, D, D, false, stream);
    gemm(x, D, Wv_l, D, v, D, S, D, D, false, stream);
    rope_k<<<(S * H * 32) / 256, 256, 0, stream>>>(q, k);
    flash_attn_k<<<dim3(S / 64, H), 256, 0, stream>>>(q, k, v, ao);
    gemm(ao, D, Wo_l, D, h, D, S, D, D, true, stream);  // h += ao @ Wo^T

    rmsnorm_k<<<S, 256, 0, stream>>>(h, ln2 + (size_t)l * D, x);
    gate_top2_k<<<S, 256, 0, stream>>>(x, gate_w + (size_t)l * E * D, comb);
    gemm(x, D, gate_projs + (size_t)l * E * I_DIM * D, D, g_all, E * I_DIM,
         S, E * I_DIM, D, false, stream);
    gemm(x, D, up_projs + (size_t)l * E * I_DIM * D, D, u_all, E * I_DIM,
         S, E * I_DIM, D, false, stream);
    silu_moe_k<<<(S * E * I_DIM) / 256, 256, 0, stream>>>(g_all, u_all, comb);
    // all-expert down-projection (K = E*I = 4096), h += ...
    mfma_gemm_k<64, 128, 1, 1><<<dim3(D / 128, S / 64), 256, 0, stream>>>(
        g_all, E * I_DIM, down_projs + (size_t)l * E * D * I_DIM, 0, h, D, E * I_DIM);
    // shared expert
    gemm(x, D, sg + (size_t)l * SI * D, D, xg, SI, S, SI, D, false, stream);
    gemm(x, D, su + (size_t)l * SI * D, D, xu, SI, S, SI, D, false, stream);
    silu2_k<<<(S * SI) / 256, 256, 0, stream>>>(xg, xu);
    gemm(xg, SI, sd + (size_t)l * D * SI, SI, h, D, S, D, SI, true, stream);  // h += t @ sd^T
  }

  rmsnorm_k<<<S, 256, 0, stream>>>(h, final_ln, x);
  init_lse_k<<<(S + 255) / 256, 256, 0, stream>>>(m_arr, l_arr, tgt_l);
  for (int c = 0; c < 8; c++) {
    int base = c * 4096;
    int cn = (c == 7) ? (V - 7 * 4096) : 4096;  // 3328 = 26*128
    gemm(x, D, lm_head + (size_t)base * D, D, logits, cn, S, cn, D, false, stream);
    lse_update_k<<<S, 256, 0, stream>>>(logits, target, m_arr, l_arr, tgt_l, base, cn);
  }
  finalize_k<<<1, 256, 0, stream>>>(m_arr, l_arr, tgt_l, target, out);
}

// Round 5
// 1570.815 us; speedup vs baseline: 5.3774x; 1.3538x over previous
//
#include <hip/hip_runtime.h>
#include <hip/hip_bf16.h>

// Problem constants (DeepSeek-V2-style scaled config)
#define S 2048
#define D 1024
#define H 16
#define DH 64
#define LAYERS 2
#define E 8
#define I_DIM 512
#define SI 1024
#define V 32000

typedef unsigned short ushort_t;
typedef __attribute__((ext_vector_type(8))) short short8;   // 8 bf16 (4 VGPRs)
typedef __attribute__((ext_vector_type(4))) float floatx4;  // MFMA accumulator

__device__ __forceinline__ float bf2f(ushort_t u) {
  union { unsigned i; float f; } x;
  x.i = ((unsigned)u) << 16;
  return x.f;
}
// f32 -> bf16 round-to-nearest-even
__device__ __forceinline__ ushort_t f2bf(float f) {
  union { float f; unsigned u; } x; x.f = f;
  unsigned r = x.u + 0x7FFFu + ((x.u >> 16) & 1u);
  return (ushort_t)(r >> 16);
}
__device__ __forceinline__ int pack2(float a, float b) {
  return (int)((unsigned)f2bf(a) | ((unsigned)f2bf(b) << 16));
}

// async global->LDS, 16 B per lane; LDS dst = base + lane*16 (wave-uniform base)
__device__ __forceinline__ void gl_lds16(const ushort_t* g, ushort_t* l) {
  __builtin_amdgcn_global_load_lds((const __attribute__((address_space(1))) void*)g,
                                   (__attribute__((address_space(3))) void*)l, 16, 0, 0);
}

// ---------------------------------------------------------------------------
// f32 -> bf16 bulk conversion (8 elems/thread)
// ---------------------------------------------------------------------------
__global__ __launch_bounds__(256) void convert_k(const float* __restrict__ in,
                                                 ushort_t* __restrict__ out, int n8) {
  int i = blockIdx.x * 256 + threadIdx.x;
  if (i >= n8) return;
  const float4* p = (const float4*)in + (size_t)i * 2;
  float4 a = p[0], b = p[1];
  int4 pk = {pack2(a.x, a.y), pack2(a.z, a.w), pack2(b.x, b.y), pack2(b.z, b.w)};
  ((int4*)out)[i] = pk;
}

// ---------------------------------------------------------------------------
// Embedding lookup (f32 residual stream)
// ---------------------------------------------------------------------------
__global__ __launch_bounds__(256) void embed_k(const int* __restrict__ tok,
                                               const float* __restrict__ emb,
                                               float* __restrict__ h) {
  int idx = blockIdx.x * 256 + threadIdx.x;
  if (idx >= S * D / 4) return;
  int s = idx >> 8;
  int d4 = idx & 255;
  int t = tok[s];
  float4 u = *(const float4*)(emb + (size_t)t * D + d4 * 4);
  *(float4*)(h + (size_t)s * D + d4 * 4) = u;
}

// ---------------------------------------------------------------------------
// RMSNorm: f32 in (residual), bf16 out (GEMM A operand)
// ---------------------------------------------------------------------------
__global__ __launch_bounds__(256) void rmsnorm_k(const float* __restrict__ h,
                                                 const float* __restrict__ w,
                                                 ushort_t* __restrict__ xb) {
  int s = blockIdx.x, tid = threadIdx.x;
  __shared__ float red[256];
  float4 hv = *(const float4*)(h + (size_t)s * D + tid * 4);
  red[tid] = hv.x * hv.x + hv.y * hv.y + hv.z * hv.z + hv.w * hv.w;
  __syncthreads();
  for (int st = 128; st > 0; st >>= 1) {
    if (tid < st) red[tid] += red[tid + st];
    __syncthreads();
  }
  float inv = rsqrtf(red[0] * (1.0f / 1024.0f) + 1e-6f);
  float4 wv = *(const float4*)(w + tid * 4);
  int2 pk;
  pk.x = pack2(hv.x * inv * wv.x, hv.y * inv * wv.y);
  pk.y = pack2(hv.z * inv * wv.z, hv.w * inv * wv.w);
  *(int2*)(xb + (size_t)s * D + tid * 4) = pk;
}

// ---------------------------------------------------------------------------
// MFMA GEMM (m97 structure): C[M,N] = A[M,K](bf16) @ B[N,K](bf16)^T
// Tile TM x TN, BK=32, 4 waves (2x2), 16x16x32 bf16 MFMA, async LDS staging.
// ACC: C(f32) += result. OUTBF: C is bf16 (no ACC). EXPERT: B = [E][D][I].
// ---------------------------------------------------------------------------
template <int TM, int TN, int ACC, int EXPERT, int OUTBF>
__global__ __launch_bounds__(256) void gbt_k(const ushort_t* __restrict__ A, int lda,
                                             const ushort_t* __restrict__ B, int ldb,
                                             void* __restrict__ Cv, int ldc, int K) {
  constexpr int WM = TM / 2, WN = TN / 2;
  constexpr int MT = WM / 16, NT = WN / 16;
  constexpr int CA = TM / 16, CB = TN / 16;   // 16-row staging chunks
  __shared__ __align__(16) ushort_t As[TM * 32];
  __shared__ __align__(16) ushort_t Bs[TN * 32];
  int tid = threadIdx.x;
  int n0 = blockIdx.x * TN, m0 = blockIdx.y * TM;
  int w = tid >> 6, lane = tid & 63, quad = lane >> 4, l16 = lane & 15;
  int wm = (w >> 1) * WM, wn = (w & 1) * WN;
  int srow = lane >> 2, sko = (lane & 3) * 8;  // staging: lane -> (row, k8)

  floatx4 acc[MT][NT];
#pragma unroll
  for (int mi = 0; mi < MT; mi++)
#pragma unroll
    for (int ni = 0; ni < NT; ni++)
      acc[mi][ni] = (floatx4){0.f, 0.f, 0.f, 0.f};

  for (int k0 = 0; k0 < K; k0 += 32) {
#pragma unroll
    for (int c = 0; c < CA; c += 4) {
      int ch = c + w;  // wave-uniform chunk id
      const ushort_t* gp = A + (size_t)(m0 + ch * 16 + srow) * lda + k0 + sko;
      gl_lds16(gp, As + ch * 512);
    }
#pragma unroll
    for (int c = 0; c < CB; c += 4) {
      int ch = c + w;
      const ushort_t* gp;
      if (EXPERT) {
        int kk = k0 + sko;
        int e = kk >> 9;  // BK=32 tile never crosses expert boundary
        gp = B + ((size_t)(e * D + n0 + ch * 16 + srow)) * I_DIM + (kk & 511);
      } else {
        gp = B + (size_t)(n0 + ch * 16 + srow) * ldb + k0 + sko;
      }
      gl_lds16(gp, Bs + ch * 512);
    }
    __syncthreads();  // drains vmcnt -> staging visible
    short8 af[MT], bfv[NT];
#pragma unroll
    for (int mi = 0; mi < MT; mi++)
      af[mi] = *(const short8*)(As + (wm + mi * 16 + l16) * 32 + quad * 8);
#pragma unroll
    for (int ni = 0; ni < NT; ni++)
      bfv[ni] = *(const short8*)(Bs + (wn + ni * 16 + l16) * 32 + quad * 8);
#pragma unroll
    for (int mi = 0; mi < MT; mi++)
#pragma unroll
      for (int ni = 0; ni < NT; ni++)
        acc[mi][ni] = __builtin_amdgcn_mfma_f32_16x16x32_bf16(af[mi], bfv[ni],
                                                              acc[mi][ni], 0, 0, 0);
    __syncthreads();  // all reads done before next staging
  }
  // epilogue: C/D layout col=lane&15, row=quad*4+r
#pragma unroll
  for (int mi = 0; mi < MT; mi++) {
#pragma unroll
    for (int ni = 0; ni < NT; ni++) {
      int row_base = m0 + wm + mi * 16 + quad * 4;
      int col = n0 + wn + ni * 16 + l16;
#pragma unroll
      for (int r = 0; r < 4; r++) {
        if (OUTBF) {
          ((ushort_t*)Cv)[(size_t)(row_base + r) * ldc + col] = f2bf(acc[mi][ni][r]);
        } else {
          float* cp = (float*)Cv + (size_t)(row_base + r) * ldc + col;
          float val = acc[mi][ni][r];
          if (ACC) val += *cp;
          *cp = val;
        }
      }
    }
  }
}

// ---------------------------------------------------------------------------
// RoPE in-place on bf16 q and k.
// ---------------------------------------------------------------------------
__global__ __launch_bounds__(256) void rope_k(ushort_t* __restrict__ q,
                                              ushort_t* __restrict__ k) {
  int idx = blockIdx.x * 256 + threadIdx.x;   // S*H*32
  int s = idx >> 9;
  int r = idx & 511;
  int hd = r >> 5, i = r & 31;
  float invf = expf(-(float)i * (9.210340371976184f / 32.0f));
  float ang = (float)s * invf;
  float c = cosf(ang), sn = sinf(ang);
  int base = s * D + hd * DH + i;
  float q1 = bf2f(q[base]), q2 = bf2f(q[base + 32]);
  q[base] = f2bf(q1 * c - q2 * sn);
  q[base + 32] = f2bf(q2 * c + q1 * sn);
  float k1 = bf2f(k[base]), k2 = bf2f(k[base + 32]);
  k[base] = f2bf(k1 * c - k2 * sn);
  k[base + 32] = f2bf(k2 * c + k1 * sn);
}

// ---------------------------------------------------------------------------
// Flash attention (MFMA), bf16 q/k/v in, bf16 out. One block per
// (64-query tile, head); wave w owns query rows [w*16, w*16+16).
// ---------------------------------------------------------------------------
#define PSTR 72
__global__ __launch_bounds__(256) void flash_attn_k(const ushort_t* __restrict__ q,
                                                    const ushort_t* __restrict__ k,
                                                    const ushort_t* __restrict__ v,
                                                    ushort_t* __restrict__ out) {
  __shared__ __align__(16) ushort_t QPs[64 * PSTR];  // Q tile, then per-wave P strips
  __shared__ __align__(16) ushort_t Ks[64 * PSTR];
  __shared__ __align__(16) ushort_t Vt[64 * PSTR];
  int qt = blockIdx.x, hh = blockIdx.y;
  int q0 = qt * 64;
  int tid = threadIdx.x;
  int w = tid >> 6, lane = tid & 63, quad = lane >> 4, l16 = lane & 15;

  // stage Q tile (64 x 64 bf16): direct copies
  {
    int row = tid >> 2, c0 = (tid & 3) * 16;
    const ushort_t* p = q + (size_t)(q0 + row) * D + hh * DH + c0;
    *(int4*)(QPs + row * PSTR + c0) = ((const int4*)p)[0];
    *(int4*)(QPs + row * PSTR + c0 + 8) = ((const int4*)p)[1];
  }
  __syncthreads();
  short8 af[2];
  af[0] = *(const short8*)(QPs + (w * 16 + l16) * PSTR + quad * 8);
  af[1] = *(const short8*)(QPs + (w * 16 + l16) * PSTR + 32 + quad * 8);

  float m_i[4], l_i[4];
  floatx4 oacc[4];
#pragma unroll
  for (int r = 0; r < 4; r++) { m_i[r] = -1e30f; l_i[r] = 0.f; }
#pragma unroll
  for (int ni = 0; ni < 4; ni++) oacc[ni] = (floatx4){0.f, 0.f, 0.f, 0.f};

  for (int kt = 0; kt <= qt; kt++) {
    int kb = kt * 64;
    __syncthreads();  // all waves done reading Ks/Vt from previous tile
    {
      int row = tid >> 2, c0 = (tid & 3) * 16;
      const ushort_t* p = k + (size_t)(kb + row) * D + hh * DH + c0;
      *(int4*)(Ks + row * PSTR + c0) = ((const int4*)p)[0];
      *(int4*)(Ks + row * PSTR + c0 + 8) = ((const int4*)p)[1];
    }
    {  // V^T: wave w covers d in [w*16, w*16+16), lane = key
      const ushort_t* p = v + (size_t)(kb + lane) * D + hh * DH + w * 16;
      ushort_t tmp[16];
      *(int4*)tmp = ((const int4*)p)[0];
      *(int4*)(tmp + 8) = ((const int4*)p)[1];
#pragma unroll
      for (int j = 0; j < 16; j++)
        Vt[(w * 16 + j) * PSTR + lane] = tmp[j];
    }
    __syncthreads();
    floatx4 sfr[4];
#pragma unroll
    for (int ni = 0; ni < 4; ni++) sfr[ni] = (floatx4){0.f, 0.f, 0.f, 0.f};
#pragma unroll
    for (int ks = 0; ks < 2; ks++) {
#pragma unroll
      for (int ni = 0; ni < 4; ni++) {
        short8 bfr = *(const short8*)(Ks + (ni * 16 + l16) * PSTR + ks * 32 + quad * 8);
        sfr[ni] = __builtin_amdgcn_mfma_f32_16x16x32_bf16(af[ks], bfr, sfr[ni], 0, 0, 0);
      }
    }
    int qrow = q0 + w * 16 + quad * 4;
#pragma unroll
    for (int ni = 0; ni < 4; ni++) {
#pragma unroll
      for (int r = 0; r < 4; r++) {
        float s = sfr[ni][r] * 0.125f;
        if (kt == qt) {
          int key = kb + ni * 16 + l16;
          if (key > qrow + r) s = -1e30f;
        }
        sfr[ni][r] = s;
      }
    }
    float tmax[4];
#pragma unroll
    for (int r = 0; r < 4; r++)
      tmax[r] = fmaxf(fmaxf(sfr[0][r], sfr[1][r]), fmaxf(sfr[2][r], sfr[3][r]));
#pragma unroll
    for (int msk = 1; msk <= 8; msk <<= 1)
#pragma unroll
      for (int r = 0; r < 4; r++)
        tmax[r] = fmaxf(tmax[r], __shfl_xor(tmax[r], msk));
    float alpha[4];
#pragma unroll
    for (int r = 0; r < 4; r++) {
      float mn = fmaxf(m_i[r], tmax[r]);
      alpha[r] = __expf(m_i[r] - mn);
      m_i[r] = mn;
    }
    float tsum[4] = {0.f, 0.f, 0.f, 0.f};
#pragma unroll
    for (int ni = 0; ni < 4; ni++) {
#pragma unroll
      for (int r = 0; r < 4; r++) {
        float p = __expf(sfr[ni][r] - m_i[r]);
        sfr[ni][r] = p;
        tsum[r] += p;
      }
    }
#pragma unroll
    for (int msk = 1; msk <= 8; msk <<= 1)
#pragma unroll
      for (int r = 0; r < 4; r++)
        tsum[r] += __shfl_xor(tsum[r], msk);
#pragma unroll
    for (int r = 0; r < 4; r++) l_i[r] = l_i[r] * alpha[r] + tsum[r];
#pragma unroll
    for (int ni = 0; ni < 4; ni++)
#pragma unroll
      for (int r = 0; r < 4; r++) oacc[ni][r] *= alpha[r];
    // P (C-layout) -> wave-private LDS strip (A-layout rows)
#pragma unroll
    for (int ni = 0; ni < 4; ni++)
#pragma unroll
      for (int r = 0; r < 4; r++)
        QPs[(w * 16 + quad * 4 + r) * PSTR + ni * 16 + l16] = f2bf(sfr[ni][r]);
    __threadfence_block();
#pragma unroll
    for (int ks = 0; ks < 2; ks++) {
      short8 pf = *(const short8*)(QPs + (w * 16 + l16) * PSTR + ks * 32 + quad * 8);
#pragma unroll
      for (int ni = 0; ni < 4; ni++) {
        short8 bfr = *(const short8*)(Vt + (ni * 16 + l16) * PSTR + ks * 32 + quad * 8);
        oacc[ni] = __builtin_amdgcn_mfma_f32_16x16x32_bf16(pf, bfr, oacc[ni], 0, 0, 0);
      }
    }
  }
#pragma unroll
  for (int r = 0; r < 4; r++) l_i[r] = 1.0f / l_i[r];
#pragma unroll
  for (int ni = 0; ni < 4; ni++) {
#pragma unroll
    for (int r = 0; r < 4; r++) {
      int row = q0 + w * 16 + quad * 4 + r;
      out[(size_t)row * D + hh * DH + ni * 16 + l16] = f2bf(oacc[ni][r] * l_i[r]);
    }
  }
}

// ---------------------------------------------------------------------------
// MoE gate: softmax(x @ gate_w^T), top-2 -> comb[s, e] (x is bf16, gw f32)
// ---------------------------------------------------------------------------
__global__ __launch_bounds__(256) void gate_top2_k(const ushort_t* __restrict__ x,
                                                   const float* __restrict__ gw,
                                                   float* __restrict__ comb) {
  int s = blockIdx.x, tid = threadIdx.x;
  __shared__ float xs[D];
  __shared__ float red[E][32];
  __shared__ float lg[E];
  for (int i = tid; i < D; i += 256) xs[i] = bf2f(x[(size_t)s * D + i]);
  __syncthreads();
  int e = tid >> 5, j = tid & 31;
  float p = 0.f;
  for (int d = j; d < D; d += 32) p += xs[d] * gw[e * D + d];
  red[e][j] = p;
  __syncthreads();
  if (tid < E) {
    float sum = 0.f;
    for (int jj = 0; jj < 32; jj++) sum += red[tid][jj];
    lg[tid] = sum;
  }
  __syncthreads();
  if (tid == 0) {
    float m = lg[0];
    for (int i = 1; i < E; i++) m = fmaxf(m, lg[i]);
    float pr[E];
    float ssum = 0.f;
    for (int i = 0; i < E; i++) { pr[i] = __expf(lg[i] - m); ssum += pr[i]; }
    float rs = 1.0f / ssum;
    for (int i = 0; i < E; i++) pr[i] *= rs;
    int b1 = 0;
    for (int i = 1; i < E; i++) if (pr[i] > pr[b1]) b1 = i;
    int b2 = -1;
    for (int i = 0; i < E; i++) {
      if (i == b1) continue;
      if (b2 < 0 || pr[i] > pr[b2]) b2 = i;
    }
    for (int i = 0; i < E; i++)
      comb[(size_t)s * E + i] = (i == b1) ? pr[b1] : ((i == b2) ? pr[b2] : 0.f);
  }
}

// act[s,e,i] = silu(g)*u*comb[s,e]  (bf16 in, bf16 out)
__global__ __launch_bounds__(256) void silu_moe_k(const ushort_t* __restrict__ g,
                                                  const ushort_t* __restrict__ u,
                                                  const float* __restrict__ comb,
                                                  ushort_t* __restrict__ act) {
  int idx = blockIdx.x * 256 + threadIdx.x;   // S*E*I
  int se = idx >> 9;
  int s = se >> 3, e = se & 7;
  float gv = bf2f(g[idx]);
  float sig = 1.0f / (1.0f + __expf(-gv));
  act[idx] = f2bf(gv * sig * bf2f(u[idx]) * comb[(size_t)s * E + e]);
}

// a = silu(a)*b  (bf16 in-place)
__global__ __launch_bounds__(256) void silu2_k(ushort_t* __restrict__ a,
                                               const ushort_t* __restrict__ b) {
  int idx = blockIdx.x * 256 + threadIdx.x;   // S*SI
  float av = bf2f(a[idx]);
  float sig = 1.0f / (1.0f + __expf(-av));
  a[idx] = f2bf(av * sig * bf2f(b[idx]));
}

// ---------------------------------------------------------------------------
// Online logsumexp over vocab chunks + final loss
// ---------------------------------------------------------------------------
__global__ __launch_bounds__(256) void init_lse_k(float* m_arr, float* l_arr, float* tgt_l) {
  int i = blockIdx.x * 256 + threadIdx.x;
  if (i < S) { m_arr[i] = -1e30f; l_arr[i] = 0.f; tgt_l[i] = 0.f; }
}

__global__ __launch_bounds__(256) void lse_update_k(const float* __restrict__ logits,
                                                    const int* __restrict__ target,
                                                    float* __restrict__ m_arr,
                                                    float* __restrict__ l_arr,
                                                    float* __restrict__ tgt_l,
                                                    int base, int cn) {
  int s = blockIdx.x, tid = threadIdx.x;
  __shared__ float red[256];
  const float* row = logits + (size_t)s * cn;
  float lm = -1e30f;
  for (int j = tid; j < cn; j += 256) lm = fmaxf(lm, row[j]);
  red[tid] = lm;
  __syncthreads();
  for (int st = 128; st > 0; st >>= 1) {
    if (tid < st) red[tid] = fmaxf(red[tid], red[tid + st]);
    __syncthreads();
  }
  float cm = red[0];
  __syncthreads();
  float ls = 0.f;
  for (int j = tid; j < cn; j += 256) ls += __expf(row[j] - cm);
  red[tid] = ls;
  __syncthreads();
  for (int st = 128; st > 0; st >>= 1) {
    if (tid < st) red[tid] += red[tid + st];
    __syncthreads();
  }
  if (tid == 0) {
    float cs = red[0];
    float m = m_arr[s], l = l_arr[s];
    float nm = fmaxf(m, cm);
    l_arr[s] = l * __expf(m - nm) + cs * __expf(cm - nm);
    m_arr[s] = nm;
    int t = target[s] - base;
    if (t >= 0 && t < cn) tgt_l[s] = row[t];
  }
}

__global__ __launch_bounds__(256) void finalize_k(const float* __restrict__ m_arr,
                                                  const float* __restrict__ l_arr,
                                                  const float* __restrict__ tgt_l,
                                                  const int* __restrict__ target,
                                                  float* __restrict__ out) {
  __shared__ float red[256];
  int tid = threadIdx.x;
  float acc = 0.f;
  for (int s = tid; s < S; s += 256) {
    if (target[s] != -100)
      acc += (logf(l_arr[s]) + m_arr[s]) - tgt_l[s];
  }
  red[tid] = acc;
  __syncthreads();
  for (int st = 128; st > 0; st >>= 1) {
    if (tid < st) red[tid] += red[tid + st];
    __syncthreads();
  }
  if (tid == 0) out[0] = red[0];
}

// ---------------------------------------------------------------------------
extern "C" void kernel_launch(void* const* d_in, const int* in_sizes, int n_in,
                              void* d_out, int out_size, void* d_ws, size_t ws_size,
                              hipStream_t stream) {
  const int* src_tokens   = (const int*)d_in[0];
  const int* target       = (const int*)d_in[1];
  const float* embed      = (const float*)d_in[2];
  const float* Wq         = (const float*)d_in[3];
  const float* Wk         = (const float*)d_in[4];
  const float* Wv         = (const float*)d_in[5];
  const float* Wo         = (const float*)d_in[6];
  const float* ln1        = (const float*)d_in[7];
  const float* ln2        = (const float*)d_in[8];
  const float* gate_w     = (const float*)d_in[9];
  const float* gate_projs = (const float*)d_in[10];
  const float* up_projs   = (const float*)d_in[11];
  const float* down_projs = (const float*)d_in[12];
  const float* sg         = (const float*)d_in[13];
  const float* su         = (const float*)d_in[14];
  const float* sd         = (const float*)d_in[15];
  const float* final_ln   = (const float*)d_in[16];
  const float* lm_head    = (const float*)d_in[17];
  float* out = (float*)d_out;

  // ---- workspace carve (~154 MB) ----
  const size_t SD = (size_t)S * D;            // 2M elems
  char* p = (char*)d_ws;
  float* h       = (float*)p;    p += SD * 4;                  // 8 MB
  ushort_t* qb   = (ushort_t*)p; p += SD * 2;
  ushort_t* kb   = (ushort_t*)p; p += SD * 2;
  ushort_t* vb   = (ushort_t*)p; p += SD * 2;
  ushort_t* xb   = (ushort_t*)p; p += SD * 2;
  ushort_t* aob  = (ushort_t*)p; p += SD * 2;
  ushort_t* g_bf = (ushort_t*)p;
  float* logits  = (float*)g_bf;  // alias: 32 MB over g_bf+u_bf (dead post-layers)
  p += (size_t)S * 4096 * 2;                                   // 16 MB
  ushort_t* u_bf   = (ushort_t*)p; p += (size_t)S * 4096 * 2;  // 16 MB
  ushort_t* act_bf = (ushort_t*)p; p += (size_t)S * 4096 * 2;  // 16 MB
  ushort_t* xgb  = (ushort_t*)p; p += SD * 2;
  ushort_t* xub  = (ushort_t*)p; p += SD * 2;
  float* comb    = (float*)p;    p += (size_t)S * E * 4;
  float* m_arr   = (float*)p;    p += S * 4;
  float* l_arr   = (float*)p;    p += S * 4;
  float* tgt_l   = (float*)p;    p += S * 4;
  ushort_t* Wq_bf = (ushort_t*)p; p += (size_t)LAYERS * D * D * 2;
  ushort_t* Wk_bf = (ushort_t*)p; p += (size_t)LAYERS * D * D * 2;
  ushort_t* Wv_bf = (ushort_t*)p; p += (size_t)LAYERS * D * D * 2;
  ushort_t* Wo_bf = (ushort_t*)p; p += (size_t)LAYERS * D * D * 2;
  ushort_t* gp_bf = (ushort_t*)p; p += (size_t)LAYERS * E * I_DIM * D * 2;
  ushort_t* up_bf = (ushort_t*)p; p += (size_t)LAYERS * E * I_DIM * D * 2;
  ushort_t* dp_bf = (ushort_t*)p; p += (size_t)LAYERS * E * D * I_DIM * 2;
  ushort_t* sg_bf = (ushort_t*)p; p += (size_t)LAYERS * SI * D * 2;
  ushort_t* su_bf = (ushort_t*)p; p += (size_t)LAYERS * SI * D * 2;
  ushort_t* sd_bf = (ushort_t*)p; p += (size_t)LAYERS * D * SI * 2;
  ushort_t* lmc   = (ushort_t*)p; p += (size_t)4096 * D * 2;   // reusable lm chunk

  // ---- weight conversions (once per launch) ----
  auto conv = [&](const float* src, ushort_t* dst, size_t n) {
    convert_k<<<(int)(n / 8 / 256), 256, 0, stream>>>(src, dst, (int)(n / 8));
  };
  conv(Wq, Wq_bf, (size_t)LAYERS * D * D);
  conv(Wk, Wk_bf, (size_t)LAYERS * D * D);
  conv(Wv, Wv_bf, (size_t)LAYERS * D * D);
  conv(Wo, Wo_bf, (size_t)LAYERS * D * D);
  conv(gate_projs, gp_bf, (size_t)LAYERS * E * I_DIM * D);
  conv(up_projs, up_bf, (size_t)LAYERS * E * I_DIM * D);
  conv(down_projs, dp_bf, (size_t)LAYERS * E * D * I_DIM);
  conv(sg, sg_bf, (size_t)LAYERS * SI * D);
  conv(su, su_bf, (size_t)LAYERS * SI * D);
  conv(sd, sd_bf, (size_t)LAYERS * D * SI);

  embed_k<<<(S * D / 4) / 256, 256, 0, stream>>>(src_tokens, embed, h);

  dim3 gN1(D / 128, S / 64);      // N=1024 shapes: 64x128 tile, 256 blocks
  dim3 gN4(4096 / 128, S / 128);  // N=4096 shapes: 128x128 tile, 512 blocks

  for (int l = 0; l < LAYERS; l++) {
    size_t wo = (size_t)l * D * D;
    rmsnorm_k<<<S, 256, 0, stream>>>(h, ln1 + (size_t)l * D, xb);
    gbt_k<64, 128, 0, 0, 1><<<gN1, 256, 0, stream>>>(xb, D, Wq_bf + wo, D, qb, D, D);
    gbt_k<64, 128, 0, 0, 1><<<gN1, 256, 0, stream>>>(xb, D, Wk_bf + wo, D, kb, D, D);
    gbt_k<64, 128, 0, 0, 1><<<gN1, 256, 0, stream>>>(xb, D, Wv_bf + wo, D, vb, D, D);
    rope_k<<<(S * H * 32) / 256, 256, 0, stream>>>(qb, kb);
    flash_attn_k<<<dim3(S / 64, H), 256, 0, stream>>>(qb, kb, vb, aob);
    gbt_k<64, 128, 1, 0, 0><<<gN1, 256, 0, stream>>>(aob, D, Wo_bf + wo, D, h, D, D);

    rmsnorm_k<<<S, 256, 0, stream>>>(h, ln2 + (size_t)l * D, xb);
    gate_top2_k<<<S, 256, 0, stream>>>(xb, gate_w + (size_t)l * E * D, comb);
    size_t go = (size_t)l * E * I_DIM * D;
    gbt_k<128, 128, 0, 0, 1><<<gN4, 256, 0, stream>>>(xb, D, gp_bf + go, D, g_bf, 4096, D);
    gbt_k<128, 128, 0, 0, 1><<<gN4, 256, 0, stream>>>(xb, D, up_bf + go, D, u_bf, 4096, D);
    silu_moe_k<<<(S * E * I_DIM) / 256, 256, 0, stream>>>(g_bf, u_bf, comb, act_bf);
    gbt_k<64, 128, 1, 1, 0><<<gN1, 256, 0, stream>>>(act_bf, E * I_DIM,
                                                     dp_bf + (size_t)l * E * D * I_DIM, 0,
                                                     h, D, E * I_DIM);
    size_t so = (size_t)l * SI * D;
    gbt_k<64, 128, 0, 0, 1><<<gN1, 256, 0, stream>>>(xb, D, sg_bf + so, D, xgb, SI, D);
    gbt_k<64, 128, 0, 0, 1><<<gN1, 256, 0, stream>>>(xb, D, su_bf + so, D, xub, SI, D);
    silu2_k<<<(S * SI) / 256, 256, 0, stream>>>(xgb, xub);
    gbt_k<64, 128, 1, 0, 0><<<gN1, 256, 0, stream>>>(xgb, SI, sd_bf + so, SI, h, D, SI);
  }

  rmsnorm_k<<<S, 256, 0, stream>>>(h, final_ln, xb);
  init_lse_k<<<(S + 255) / 256, 256, 0, stream>>>(m_arr, l_arr, tgt_l);
  for (int c = 0; c < 8; c++) {
    int base = c * 4096;
    int cn = (c == 7) ? (V - 7 * 4096) : 4096;  // 3328 = 26*128
    conv(lm_head + (size_t)base * D, lmc, (size_t)cn * D);
    gbt_k<128, 128, 0, 0, 0><<<dim3(cn / 128, S / 128), 256, 0, stream>>>(
        xb, D, lmc, D, logits, cn, D);
    lse_update_k<<<S, 256, 0, stream>>>(logits, target, m_arr, l_arr, tgt_l, base, cn);
  }
  finalize_k<<<1, 256, 0, stream>>>(m_arr, l_arr, tgt_l, target, out);
}

// Round 6
// 1486.088 us; speedup vs baseline: 5.6840x; 1.0570x over previous
//
#include <hip/hip_runtime.h>
#include <hip/hip_bf16.h>

// Problem constants (DeepSeek-V2-style scaled config)
#define S 2048
#define D 1024
#define H 16
#define DH 64
#define LAYERS 2
#define E 8
#define I_DIM 512
#define SI 1024
#define V 32000
#define NSTRIP 125   // V / 256

typedef unsigned short ushort_t;
typedef __attribute__((ext_vector_type(8))) short short8;   // 8 bf16 (4 VGPRs)
typedef __attribute__((ext_vector_type(4))) float floatx4;  // MFMA accumulator

__device__ __forceinline__ float bf2f(ushort_t u) {
  union { unsigned i; float f; } x;
  x.i = ((unsigned)u) << 16;
  return x.f;
}
__device__ __forceinline__ ushort_t f2bf(float f) {
  union { float f; unsigned u; } x; x.f = f;
  unsigned r = x.u + 0x7FFFu + ((x.u >> 16) & 1u);
  return (ushort_t)(r >> 16);
}
__device__ __forceinline__ int pack2(float a, float b) {
  return (int)((unsigned)f2bf(a) | ((unsigned)f2bf(b) << 16));
}

// async global->LDS, 16 B per lane; LDS dst = wave-uniform base + lane*16
__device__ __forceinline__ void gl_lds16(const ushort_t* g, ushort_t* l) {
  __builtin_amdgcn_global_load_lds((const __attribute__((address_space(1))) void*)g,
                                   (__attribute__((address_space(3))) void*)l, 16, 0, 0);
}

// ---------------------------------------------------------------------------
__global__ __launch_bounds__(256) void convert_k(const float* __restrict__ in,
                                                 ushort_t* __restrict__ out, int n8) {
  int i = blockIdx.x * 256 + threadIdx.x;
  if (i >= n8) return;
  const float4* p = (const float4*)in + (size_t)i * 2;
  float4 a = p[0], b = p[1];
  int4 pk = {pack2(a.x, a.y), pack2(a.z, a.w), pack2(b.x, b.y), pack2(b.z, b.w)};
  ((int4*)out)[i] = pk;
}

__global__ __launch_bounds__(256) void embed_k(const int* __restrict__ tok,
                                               const float* __restrict__ emb,
                                               float* __restrict__ h) {
  int idx = blockIdx.x * 256 + threadIdx.x;
  if (idx >= S * D / 4) return;
  int s = idx >> 8;
  int d4 = idx & 255;
  int t = tok[s];
  float4 u = *(const float4*)(emb + (size_t)t * D + d4 * 4);
  *(float4*)(h + (size_t)s * D + d4 * 4) = u;
}

__global__ __launch_bounds__(256) void rmsnorm_k(const float* __restrict__ h,
                                                 const float* __restrict__ w,
                                                 ushort_t* __restrict__ xb) {
  int s = blockIdx.x, tid = threadIdx.x;
  __shared__ float red[256];
  float4 hv = *(const float4*)(h + (size_t)s * D + tid * 4);
  red[tid] = hv.x * hv.x + hv.y * hv.y + hv.z * hv.z + hv.w * hv.w;
  __syncthreads();
  for (int st = 128; st > 0; st >>= 1) {
    if (tid < st) red[tid] += red[tid + st];
    __syncthreads();
  }
  float inv = rsqrtf(red[0] * (1.0f / 1024.0f) + 1e-6f);
  float4 wv = *(const float4*)(w + tid * 4);
  int2 pk;
  pk.x = pack2(hv.x * inv * wv.x, hv.y * inv * wv.y);
  pk.y = pack2(hv.z * inv * wv.z, hv.w * inv * wv.w);
  *(int2*)(xb + (size_t)s * D + tid * 4) = pk;
}

// ---------------------------------------------------------------------------
// MFMA GEMM (m97 structure): C[M,N] = A[M,K](bf16) @ B[N,K](bf16)^T
// Tile TM x TN, BK=32, 4 waves (2x2), 16x16x32 bf16 MFMA, async LDS staging.
// MODE 0: f32 store; 1: bf16 store; 2: f32 accumulate. EXPERT: B = [E][D][I].
// ---------------------------------------------------------------------------
template <int TM, int TN, int MODE, int EXPERT>
__global__ __launch_bounds__(256) void gbt_k(const ushort_t* __restrict__ A, int lda,
                                             const ushort_t* __restrict__ B, int ldb,
                                             void* __restrict__ Cv, int ldc, int K) {
  constexpr int WM = TM / 2, WN = TN / 2;
  constexpr int MT = WM / 16, NT = WN / 16;
  constexpr int CA = TM / 16, CB = TN / 16;
  __shared__ __align__(16) ushort_t As[TM * 32];
  __shared__ __align__(16) ushort_t Bs[TN * 32];
  int tid = threadIdx.x;
  int n0 = blockIdx.x * TN, m0 = blockIdx.y * TM;
  int w = tid >> 6, lane = tid & 63, quad = lane >> 4, l16 = lane & 15;
  int wm = (w >> 1) * WM, wn = (w & 1) * WN;
  int srow = lane >> 2, sko = (lane & 3) * 8;

  floatx4 acc[MT][NT];
#pragma unroll
  for (int mi = 0; mi < MT; mi++)
#pragma unroll
    for (int ni = 0; ni < NT; ni++)
      acc[mi][ni] = (floatx4){0.f, 0.f, 0.f, 0.f};

  for (int k0 = 0; k0 < K; k0 += 32) {
#pragma unroll
    for (int c = 0; c < CA; c += 4) {
      int ch = c + w;
      const ushort_t* gp = A + (size_t)(m0 + ch * 16 + srow) * lda + k0 + sko;
      gl_lds16(gp, As + ch * 512);
    }
#pragma unroll
    for (int c = 0; c < CB; c += 4) {
      int ch = c + w;
      const ushort_t* gp;
      if (EXPERT) {
        int kk = k0 + sko;
        int e = kk >> 9;
        gp = B + ((size_t)(e * D + n0 + ch * 16 + srow)) * I_DIM + (kk & 511);
      } else {
        gp = B + (size_t)(n0 + ch * 16 + srow) * ldb + k0 + sko;
      }
      gl_lds16(gp, Bs + ch * 512);
    }
    __syncthreads();
    short8 af[MT], bfv[NT];
#pragma unroll
    for (int mi = 0; mi < MT; mi++)
      af[mi] = *(const short8*)(As + (wm + mi * 16 + l16) * 32 + quad * 8);
#pragma unroll
    for (int ni = 0; ni < NT; ni++)
      bfv[ni] = *(const short8*)(Bs + (wn + ni * 16 + l16) * 32 + quad * 8);
#pragma unroll
    for (int mi = 0; mi < MT; mi++)
#pragma unroll
      for (int ni = 0; ni < NT; ni++)
        acc[mi][ni] = __builtin_amdgcn_mfma_f32_16x16x32_bf16(af[mi], bfv[ni],
                                                              acc[mi][ni], 0, 0, 0);
    __syncthreads();
  }
#pragma unroll
  for (int mi = 0; mi < MT; mi++) {
#pragma unroll
    for (int ni = 0; ni < NT; ni++) {
      int row_base = m0 + wm + mi * 16 + quad * 4;
      int col = n0 + wn + ni * 16 + l16;
#pragma unroll
      for (int r = 0; r < 4; r++) {
        if (MODE == 1) {
          ((ushort_t*)Cv)[(size_t)(row_base + r) * ldc + col] = f2bf(acc[mi][ni][r]);
        } else {
          float* cp = (float*)Cv + (size_t)(row_base + r) * ldc + col;
          float val = acc[mi][ni][r];
          if (MODE == 2) val += *cp;
          *cp = val;
        }
      }
    }
  }
}

// ---------------------------------------------------------------------------
// LM-head GEMM with fused LSE epilogue. TM=128, TN=256. Never writes logits:
// each block emits per-row (max, sumexp) over its 256-col strip + target logit.
// ---------------------------------------------------------------------------
__global__ __launch_bounds__(256) void lmhead_lse_k(const ushort_t* __restrict__ A,
                                                    const ushort_t* __restrict__ B,
                                                    const int* __restrict__ target,
                                                    float2* __restrict__ partial,
                                                    float* __restrict__ tgt_l,
                                                    int strip_base) {
  constexpr int TM = 128, TN = 256;
  constexpr int WM = 64, WN = 128, MT = 4, NT = 8;
  __shared__ __align__(16) ushort_t As[TM * 32];
  __shared__ __align__(16) ushort_t Bs[TN * 32];
  int tid = threadIdx.x;
  int n0 = blockIdx.x * TN, m0 = blockIdx.y * TM;
  int w = tid >> 6, lane = tid & 63, quad = lane >> 4, l16 = lane & 15;
  int wm = (w >> 1) * WM, wn = (w & 1) * WN;
  int srow = lane >> 2, sko = (lane & 3) * 8;

  floatx4 acc[MT][NT];
#pragma unroll
  for (int mi = 0; mi < MT; mi++)
#pragma unroll
    for (int ni = 0; ni < NT; ni++)
      acc[mi][ni] = (floatx4){0.f, 0.f, 0.f, 0.f};

  for (int k0 = 0; k0 < D; k0 += 32) {
#pragma unroll
    for (int c = 0; c < 8; c += 4)
      gl_lds16(A + (size_t)(m0 + (c + w) * 16 + srow) * D + k0 + sko, As + (c + w) * 512);
#pragma unroll
    for (int c = 0; c < 16; c += 4)
      gl_lds16(B + (size_t)(n0 + (c + w) * 16 + srow) * D + k0 + sko, Bs + (c + w) * 512);
    __syncthreads();
    short8 af[MT], bfv[NT];
#pragma unroll
    for (int mi = 0; mi < MT; mi++)
      af[mi] = *(const short8*)(As + (wm + mi * 16 + l16) * 32 + quad * 8);
#pragma unroll
    for (int ni = 0; ni < NT; ni++)
      bfv[ni] = *(const short8*)(Bs + (wn + ni * 16 + l16) * 32 + quad * 8);
#pragma unroll
    for (int mi = 0; mi < MT; mi++)
#pragma unroll
      for (int ni = 0; ni < NT; ni++)
        acc[mi][ni] = __builtin_amdgcn_mfma_f32_16x16x32_bf16(af[mi], bfv[ni],
                                                              acc[mi][ni], 0, 0, 0);
    __syncthreads();
  }
  // ---- fused LSE epilogue ----
  __shared__ float pm[128][2], pl[128][2];
  __shared__ int tgts[128];
  int n0g = (strip_base + blockIdx.x) * TN;  // global col base
  if (tid < 128) tgts[tid] = target[m0 + tid];
  __syncthreads();
#pragma unroll
  for (int mi = 0; mi < MT; mi++) {
    float rmax[4], rsum[4];
#pragma unroll
    for (int r = 0; r < 4; r++) {
      float m = acc[mi][0][r];
#pragma unroll
      for (int ni = 1; ni < NT; ni++) m = fmaxf(m, acc[mi][ni][r]);
      rmax[r] = m;
    }
#pragma unroll
    for (int msk = 1; msk <= 8; msk <<= 1)
#pragma unroll
      for (int r = 0; r < 4; r++)
        rmax[r] = fmaxf(rmax[r], __shfl_xor(rmax[r], msk));
#pragma unroll
    for (int r = 0; r < 4; r++) {
      float s = 0.f;
#pragma unroll
      for (int ni = 0; ni < NT; ni++) s += __expf(acc[mi][ni][r] - rmax[r]);
      rsum[r] = s;
    }
#pragma unroll
    for (int msk = 1; msk <= 8; msk <<= 1)
#pragma unroll
      for (int r = 0; r < 4; r++)
        rsum[r] += __shfl_xor(rsum[r], msk);
    // target capture (each logit visited exactly once across the grid)
    int rib = wm + mi * 16 + quad * 4;
#pragma unroll
    for (int r = 0; r < 4; r++) {
      int t = tgts[rib + r];
#pragma unroll
      for (int ni = 0; ni < NT; ni++) {
        int colg = n0g + wn + ni * 16 + l16;
        if (t == colg) tgt_l[m0 + rib + r] = acc[mi][ni][r];
      }
    }
    if (l16 == 0) {
#pragma unroll
      for (int r = 0; r < 4; r++) {
        pm[rib + r][w & 1] = rmax[r];
        pl[rib + r][w & 1] = rsum[r];
      }
    }
  }
  __syncthreads();
  if (tid < 128) {
    float m0v = pm[tid][0], m1v = pm[tid][1];
    float m = fmaxf(m0v, m1v);
    float l = pl[tid][0] * __expf(m0v - m) + pl[tid][1] * __expf(m1v - m);
    partial[(size_t)(m0 + tid) * NSTRIP + strip_base + blockIdx.x] = make_float2(m, l);
  }
}

__global__ __launch_bounds__(256) void reduce_lse_k(const float2* __restrict__ partial,
                                                    const int* __restrict__ target,
                                                    const float* __restrict__ tgt_l,
                                                    float* __restrict__ nll) {
  int row = blockIdx.x * 256 + threadIdx.x;
  if (row >= S) return;
  float m = -1e30f, l = 0.f;
  for (int j = 0; j < NSTRIP; j++) {
    float2 pp = partial[(size_t)row * NSTRIP + j];
    float nm = fmaxf(m, pp.x);
    l = l * __expf(m - nm) + pp.y * __expf(pp.x - nm);
    m = nm;
  }
  int t = target[row];
  nll[row] = (t != -100) ? (logf(l) + m - tgt_l[row]) : 0.f;
}

__global__ __launch_bounds__(256) void sum_nll_k(const float* __restrict__ nll,
                                                 float* __restrict__ out) {
  __shared__ float red[256];
  int tid = threadIdx.x;
  float acc = 0.f;
  for (int s = tid; s < S; s += 256) acc += nll[s];
  red[tid] = acc;
  __syncthreads();
  for (int st = 128; st > 0; st >>= 1) {
    if (tid < st) red[tid] += red[tid + st];
    __syncthreads();
  }
  if (tid == 0) out[0] = red[0];
}

// ---------------------------------------------------------------------------
// RoPE in-place on fused qkv buffer (row stride 3072; k at col offset 1024).
// ---------------------------------------------------------------------------
__global__ __launch_bounds__(256) void rope_k(ushort_t* __restrict__ qkv) {
  int idx = blockIdx.x * 256 + threadIdx.x;   // S*H*32
  int s = idx >> 9;
  int r = idx & 511;
  int hd = r >> 5, i = r & 31;
  float invf = expf(-(float)i * (9.210340371976184f / 32.0f));
  float ang = (float)s * invf;
  float c = cosf(ang), sn = sinf(ang);
  size_t base = (size_t)s * 3072 + hd * DH + i;
  float q1 = bf2f(qkv[base]), q2 = bf2f(qkv[base + 32]);
  qkv[base] = f2bf(q1 * c - q2 * sn);
  qkv[base + 32] = f2bf(q2 * c + q1 * sn);
  float k1 = bf2f(qkv[base + 1024]), k2 = bf2f(qkv[base + 1024 + 32]);
  qkv[base + 1024] = f2bf(k1 * c - k2 * sn);
  qkv[base + 1024 + 32] = f2bf(k2 * c + k1 * sn);
}

// ---------------------------------------------------------------------------
// Flash attention (MFMA), q/k/v rows stride 3072 (fused qkv), out stride D.
// ---------------------------------------------------------------------------
#define PSTR 72
__global__ __launch_bounds__(256) void flash_attn_k(const ushort_t* __restrict__ q,
                                                    const ushort_t* __restrict__ k,
                                                    const ushort_t* __restrict__ v,
                                                    ushort_t* __restrict__ out) {
  __shared__ __align__(16) ushort_t QPs[64 * PSTR];
  __shared__ __align__(16) ushort_t Ks[64 * PSTR];
  __shared__ __align__(16) ushort_t Vt[64 * PSTR];
  int qt = blockIdx.x, hh = blockIdx.y;
  int q0 = qt * 64;
  int tid = threadIdx.x;
  int w = tid >> 6, lane = tid & 63, quad = lane >> 4, l16 = lane & 15;

  {
    int row = tid >> 2, c0 = (tid & 3) * 16;
    const ushort_t* p = q + (size_t)(q0 + row) * 3072 + hh * DH + c0;
    *(int4*)(QPs + row * PSTR + c0) = ((const int4*)p)[0];
    *(int4*)(QPs + row * PSTR + c0 + 8) = ((const int4*)p)[1];
  }
  __syncthreads();
  short8 af[2];
  af[0] = *(const short8*)(QPs + (w * 16 + l16) * PSTR + quad * 8);
  af[1] = *(const short8*)(QPs + (w * 16 + l16) * PSTR + 32 + quad * 8);

  float m_i[4], l_i[4];
  floatx4 oacc[4];
#pragma unroll
  for (int r = 0; r < 4; r++) { m_i[r] = -1e30f; l_i[r] = 0.f; }
#pragma unroll
  for (int ni = 0; ni < 4; ni++) oacc[ni] = (floatx4){0.f, 0.f, 0.f, 0.f};

  for (int kt = 0; kt <= qt; kt++) {
    int kb = kt * 64;
    __syncthreads();
    {
      int row = tid >> 2, c0 = (tid & 3) * 16;
      const ushort_t* p = k + (size_t)(kb + row) * 3072 + hh * DH + c0;
      *(int4*)(Ks + row * PSTR + c0) = ((const int4*)p)[0];
      *(int4*)(Ks + row * PSTR + c0 + 8) = ((const int4*)p)[1];
    }
    {
      const ushort_t* p = v + (size_t)(kb + lane) * 3072 + hh * DH + w * 16;
      ushort_t tmp[16];
      *(int4*)tmp = ((const int4*)p)[0];
      *(int4*)(tmp + 8) = ((const int4*)p)[1];
#pragma unroll
      for (int j = 0; j < 16; j++)
        Vt[(w * 16 + j) * PSTR + lane] = tmp[j];
    }
    __syncthreads();
    floatx4 sfr[4];
#pragma unroll
    for (int ni = 0; ni < 4; ni++) sfr[ni] = (floatx4){0.f, 0.f, 0.f, 0.f};
#pragma unroll
    for (int ks = 0; ks < 2; ks++) {
#pragma unroll
      for (int ni = 0; ni < 4; ni++) {
        short8 bfr = *(const short8*)(Ks + (ni * 16 + l16) * PSTR + ks * 32 + quad * 8);
        sfr[ni] = __builtin_amdgcn_mfma_f32_16x16x32_bf16(af[ks], bfr, sfr[ni], 0, 0, 0);
      }
    }
    int qrow = q0 + w * 16 + quad * 4;
#pragma unroll
    for (int ni = 0; ni < 4; ni++) {
#pragma unroll
      for (int r = 0; r < 4; r++) {
        float s = sfr[ni][r] * 0.125f;
        if (kt == qt) {
          int key = kb + ni * 16 + l16;
          if (key > qrow + r) s = -1e30f;
        }
        sfr[ni][r] = s;
      }
    }
    float tmax[4];
#pragma unroll
    for (int r = 0; r < 4; r++)
      tmax[r] = fmaxf(fmaxf(sfr[0][r], sfr[1][r]), fmaxf(sfr[2][r], sfr[3][r]));
#pragma unroll
    for (int msk = 1; msk <= 8; msk <<= 1)
#pragma unroll
      for (int r = 0; r < 4; r++)
        tmax[r] = fmaxf(tmax[r], __shfl_xor(tmax[r], msk));
    float alpha[4];
#pragma unroll
    for (int r = 0; r < 4; r++) {
      float mn = fmaxf(m_i[r], tmax[r]);
      alpha[r] = __expf(m_i[r] - mn);
      m_i[r] = mn;
    }
    float tsum[4] = {0.f, 0.f, 0.f, 0.f};
#pragma unroll
    for (int ni = 0; ni < 4; ni++) {
#pragma unroll
      for (int r = 0; r < 4; r++) {
        float p = __expf(sfr[ni][r] - m_i[r]);
        sfr[ni][r] = p;
        tsum[r] += p;
      }
    }
#pragma unroll
    for (int msk = 1; msk <= 8; msk <<= 1)
#pragma unroll
      for (int r = 0; r < 4; r++)
        tsum[r] += __shfl_xor(tsum[r], msk);
#pragma unroll
    for (int r = 0; r < 4; r++) l_i[r] = l_i[r] * alpha[r] + tsum[r];
#pragma unroll
    for (int ni = 0; ni < 4; ni++)
#pragma unroll
      for (int r = 0; r < 4; r++) oacc[ni][r] *= alpha[r];
#pragma unroll
    for (int ni = 0; ni < 4; ni++)
#pragma unroll
      for (int r = 0; r < 4; r++)
        QPs[(w * 16 + quad * 4 + r) * PSTR + ni * 16 + l16] = f2bf(sfr[ni][r]);
    __threadfence_block();
#pragma unroll
    for (int ks = 0; ks < 2; ks++) {
      short8 pf = *(const short8*)(QPs + (w * 16 + l16) * PSTR + ks * 32 + quad * 8);
#pragma unroll
      for (int ni = 0; ni < 4; ni++) {
        short8 bfr = *(const short8*)(Vt + (ni * 16 + l16) * PSTR + ks * 32 + quad * 8);
        oacc[ni] = __builtin_amdgcn_mfma_f32_16x16x32_bf16(pf, bfr, oacc[ni], 0, 0, 0);
      }
    }
  }
#pragma unroll
  for (int r = 0; r < 4; r++) l_i[r] = 1.0f / l_i[r];
#pragma unroll
  for (int ni = 0; ni < 4; ni++) {
#pragma unroll
    for (int r = 0; r < 4; r++) {
      int row = q0 + w * 16 + quad * 4 + r;
      out[(size_t)row * D + hh * DH + ni * 16 + l16] = f2bf(oacc[ni][r] * l_i[r]);
    }
  }
}

// ---------------------------------------------------------------------------
__global__ __launch_bounds__(256) void gate_top2_k(const ushort_t* __restrict__ x,
                                                   const float* __restrict__ gw,
                                                   float* __restrict__ comb) {
  int s = blockIdx.x, tid = threadIdx.x;
  __shared__ float xs[D];
  __shared__ float red[E][32];
  __shared__ float lg[E];
  for (int i = tid; i < D; i += 256) xs[i] = bf2f(x[(size_t)s * D + i]);
  __syncthreads();
  int e = tid >> 5, j = tid & 31;
  float p = 0.f;
  for (int d = j; d < D; d += 32) p += xs[d] * gw[e * D + d];
  red[e][j] = p;
  __syncthreads();
  if (tid < E) {
    float sum = 0.f;
    for (int jj = 0; jj < 32; jj++) sum += red[tid][jj];
    lg[tid] = sum;
  }
  __syncthreads();
  if (tid == 0) {
    float m = lg[0];
    for (int i = 1; i < E; i++) m = fmaxf(m, lg[i]);
    float pr[E];
    float ssum = 0.f;
    for (int i = 0; i < E; i++) { pr[i] = __expf(lg[i] - m); ssum += pr[i]; }
    float rs = 1.0f / ssum;
    for (int i = 0; i < E; i++) pr[i] *= rs;
    int b1 = 0;
    for (int i = 1; i < E; i++) if (pr[i] > pr[b1]) b1 = i;
    int b2 = -1;
    for (int i = 0; i < E; i++) {
      if (i == b1) continue;
      if (b2 < 0 || pr[i] > pr[b2]) b2 = i;
    }
    for (int i = 0; i < E; i++)
      comb[(size_t)s * E + i] = (i == b1) ? pr[b1] : ((i == b2) ? pr[b2] : 0.f);
  }
}

// act[s,e,i] = silu(g)*u*comb; gu rows stride 8192 (g cols 0..4095, u 4096..)
__global__ __launch_bounds__(256) void silu_moe_k(const ushort_t* __restrict__ gu,
                                                  const float* __restrict__ comb,
                                                  ushort_t* __restrict__ act) {
  int idx = blockIdx.x * 256 + threadIdx.x;   // S*4096
  int s = idx >> 12, rem = idx & 4095;
  int e = rem >> 9;
  size_t gi = (size_t)s * 8192 + rem;
  float gv = bf2f(gu[gi]);
  float sig = 1.0f / (1.0f + __expf(-gv));
  act[idx] = f2bf(gv * sig * bf2f(gu[gi + 4096]) * comb[(size_t)s * E + e]);
}

// xgu rows stride 2048: cols 0..1023 = sg result, 1024.. = su result.
// In-place: xgu[s][i] = silu(xgu[s][i]) * xgu[s][1024+i]
__global__ __launch_bounds__(256) void silu2_k(ushort_t* __restrict__ xgu) {
  int idx = blockIdx.x * 256 + threadIdx.x;   // S*SI
  int s = idx >> 10, i = idx & 1023;
  size_t a = (size_t)s * 2048 + i;
  float av = bf2f(xgu[a]);
  float sig = 1.0f / (1.0f + __expf(-av));
  xgu[a] = f2bf(av * sig * bf2f(xgu[a + 1024]));
}

// ---------------------------------------------------------------------------
extern "C" void kernel_launch(void* const* d_in, const int* in_sizes, int n_in,
                              void* d_out, int out_size, void* d_ws, size_t ws_size,
                              hipStream_t stream) {
  const int* src_tokens   = (const int*)d_in[0];
  const int* target       = (const int*)d_in[1];
  const float* embed      = (const float*)d_in[2];
  const float* Wq         = (const float*)d_in[3];
  const float* Wk         = (const float*)d_in[4];
  const float* Wv         = (const float*)d_in[5];
  const float* Wo         = (const float*)d_in[6];
  const float* ln1        = (const float*)d_in[7];
  const float* ln2        = (const float*)d_in[8];
  const float* gate_w     = (const float*)d_in[9];
  const float* gate_projs = (const float*)d_in[10];
  const float* up_projs   = (const float*)d_in[11];
  const float* down_projs = (const float*)d_in[12];
  const float* sg         = (const float*)d_in[13];
  const float* su         = (const float*)d_in[14];
  const float* sd         = (const float*)d_in[15];
  const float* final_ln   = (const float*)d_in[16];
  const float* lm_head    = (const float*)d_in[17];
  float* out = (float*)d_out;

  // ---- workspace carve (~140 MB) ----
  const size_t SD = (size_t)S * D;
  char* p = (char*)d_ws;
  float* h        = (float*)p;    p += SD * 4;                       // 8 MB
  ushort_t* qkvb  = (ushort_t*)p; p += (size_t)S * 3072 * 2;         // 12 MB
  ushort_t* xb    = (ushort_t*)p; p += SD * 2;                       // 4 MB
  ushort_t* aob   = (ushort_t*)p; p += SD * 2;                       // 4 MB
  ushort_t* gu    = (ushort_t*)p; p += (size_t)S * 8192 * 2;         // 33.5 MB
  ushort_t* act_bf= (ushort_t*)p; p += (size_t)S * 4096 * 2;         // 16.8 MB
  ushort_t* xgu   = (ushort_t*)p; p += (size_t)S * 2048 * 2;         // 8.4 MB
  float* comb     = (float*)p;    p += (size_t)S * E * 4;
  float* tgt_l    = (float*)p;    p += S * 4;
  float* nll      = (float*)p;    p += S * 4;
  float2* partial = (float2*)p;   p += (size_t)S * NSTRIP * 8;       // 2 MB
  ushort_t* qkv_w = (ushort_t*)p; p += (size_t)LAYERS * 3072 * D * 2;
  ushort_t* Wo_bf = (ushort_t*)p; p += (size_t)LAYERS * D * D * 2;
  ushort_t* gu_w  = (ushort_t*)p; p += (size_t)LAYERS * 8192 * D * 2;
  ushort_t* dp_bf = (ushort_t*)p; p += (size_t)LAYERS * E * D * I_DIM * 2;
  ushort_t* sgsu_w= (ushort_t*)p; p += (size_t)LAYERS * 2048 * D * 2;
  ushort_t* sd_bf = (ushort_t*)p; p += (size_t)LAYERS * D * SI * 2;
  ushort_t* lmc   = gu;  // lm chunk (<=33.6 MB) aliases gu+act (dead in lm phase)

  auto conv = [&](const float* src, ushort_t* dst, size_t n) {
    convert_k<<<(int)(n / 8 / 256), 256, 0, stream>>>(src, dst, (int)(n / 8));
  };
  const size_t DD = (size_t)D * D;
  for (int l = 0; l < LAYERS; l++) {
    conv(Wq + l * DD, qkv_w + (size_t)l * 3072 * D, DD);
    conv(Wk + l * DD, qkv_w + (size_t)l * 3072 * D + 1024 * D, DD);
    conv(Wv + l * DD, qkv_w + (size_t)l * 3072 * D + 2048 * D, DD);
    conv(gate_projs + (size_t)l * 4096 * D, gu_w + (size_t)l * 8192 * D, 4096 * (size_t)D);
    conv(up_projs + (size_t)l * 4096 * D, gu_w + (size_t)l * 8192 * D + 4096 * D, 4096 * (size_t)D);
    conv(sg + l * (size_t)SI * D, sgsu_w + (size_t)l * 2048 * D, (size_t)SI * D);
    conv(su + l * (size_t)SI * D, sgsu_w + (size_t)l * 2048 * D + 1024 * D, (size_t)SI * D);
  }
  conv(Wo, Wo_bf, LAYERS * DD);
  conv(down_projs, dp_bf, (size_t)LAYERS * E * D * I_DIM);
  conv(sd, sd_bf, (size_t)LAYERS * D * SI);

  embed_k<<<(S * D / 4) / 256, 256, 0, stream>>>(src_tokens, embed, h);

  for (int l = 0; l < LAYERS; l++) {
    rmsnorm_k<<<S, 256, 0, stream>>>(h, ln1 + (size_t)l * D, xb);
    // fused QKV: N=3072
    gbt_k<64, 128, 1, 0><<<dim3(3072 / 128, S / 64), 256, 0, stream>>>(
        xb, D, qkv_w + (size_t)l * 3072 * D, D, qkvb, 3072, D);
    rope_k<<<(S * H * 32) / 256, 256, 0, stream>>>(qkvb);
    flash_attn_k<<<dim3(S / 64, H), 256, 0, stream>>>(qkvb, qkvb + 1024, qkvb + 2048, aob);
    gbt_k<64, 128, 2, 0><<<dim3(D / 128, S / 64), 256, 0, stream>>>(
        aob, D, Wo_bf + (size_t)l * DD, D, h, D, D);

    rmsnorm_k<<<S, 256, 0, stream>>>(h, ln2 + (size_t)l * D, xb);
    gate_top2_k<<<S, 256, 0, stream>>>(xb, gate_w + (size_t)l * E * D, comb);
    // fused gate+up: N=8192, 128x256 tiles
    gbt_k<128, 256, 1, 0><<<dim3(8192 / 256, S / 128), 256, 0, stream>>>(
        xb, D, gu_w + (size_t)l * 8192 * D, D, gu, 8192, D);
    silu_moe_k<<<(S * 4096) / 256, 256, 0, stream>>>(gu, comb, act_bf);
    gbt_k<64, 128, 2, 1><<<dim3(D / 128, S / 64), 256, 0, stream>>>(
        act_bf, E * I_DIM, dp_bf + (size_t)l * E * D * I_DIM, 0, h, D, E * I_DIM);
    // fused shared-expert sg+su: N=2048
    gbt_k<64, 128, 1, 0><<<dim3(2048 / 128, S / 64), 256, 0, stream>>>(
        xb, D, sgsu_w + (size_t)l * 2048 * D, D, xgu, 2048, D);
    silu2_k<<<(S * SI) / 256, 256, 0, stream>>>(xgu);
    gbt_k<64, 128, 2, 0><<<dim3(D / 128, S / 64), 256, 0, stream>>>(
        xgu, 2048, sd_bf + (size_t)l * D * SI, SI, h, D, SI);
  }

  rmsnorm_k<<<S, 256, 0, stream>>>(h, final_ln, xb);
  // LM head in 2 chunks (64 + 61 strips of 256 cols), fused LSE epilogue
  {
    conv(lm_head, lmc, (size_t)16384 * D);
    lmhead_lse_k<<<dim3(64, S / 128), 256, 0, stream>>>(xb, lmc, target, partial, tgt_l, 0);
    conv(lm_head + (size_t)16384 * D, lmc, (size_t)15616 * D);
    lmhead_lse_k<<<dim3(61, S / 128), 256, 0, stream>>>(xb, lmc, target, partial, tgt_l, 64);
  }
  reduce_lse_k<<<S / 256, 256, 0, stream>>>(partial, target, tgt_l, nll);
  sum_nll_k<<<1, 256, 0, stream>>>(nll, out);
}